// Round 7
// baseline (1690.434 us; speedup 1.0000x reference)
//
#include <hip/hip_runtime.h>
#include <hip/hip_bf16.h>
#include <math.h>

#define NN 50000
#define EE 800000
#define HH 128
#define FF 128
#define GG 50
#define LL 6
#define H2D 64
#define OUT_DIM 12
#define NK 1024          // table intervals; knots = NK+1, stride 1026 rows/layer
#define NBLK 782         // ceil(NN/64)
#define SB 196           // scan blocks: ceil(NN/256)

typedef __bf16 bf16;
typedef __attribute__((ext_vector_type(8))) __bf16 bf16x8;
typedef __attribute__((ext_vector_type(2))) __bf16 bf16x2;
typedef __attribute__((ext_vector_type(4))) float f32x4;

#define DEV __device__ __forceinline__

DEV float sspf(float x) {
    return fmaxf(x, 0.f) + log1pf(__expf(-fabsf(x))) - 0.69314718055994531f;
}

DEV f32x4 mfma16(bf16x8 a, bf16x8 b, f32x4 c) {
    return __builtin_amdgcn_mfma_f32_16x16x32_bf16(a, b, c, 0, 0, 0);
}

DEV float blo(unsigned u) { return __uint_as_float(u << 16); }
DEV float bhi(unsigned u) { return __uint_as_float(u & 0xffff0000u); }

// -------- prep: transpose node-GEMM weights to [n][k] bf16 -------------------
struct PrepArgs {
    const float *conv1_w, *conv2_w, *int_lin_w, *lin1_w, *lin2_w;
    bf16 *c1t, *c2t, *ilt, *l1t, *l2t;
};

__global__ void prep_kernel(PrepArgs p) {
    int j = blockIdx.x;
    const float* src = nullptr; bf16* dst = nullptr; int R = 0, C = 0, K = 0;
    if (j < 18) {
        int l = j / 3, m = j % 3;
        switch (m) {
            case 0: src = p.conv1_w + l * HH * FF;   dst = p.c1t + l * FF * HH;  R = HH; C = FF; K = HH; break;
            case 1: src = p.conv2_w + l * FF * HH;   dst = p.c2t + l * HH * FF;  R = FF; C = HH; K = FF; break;
            case 2: src = p.int_lin_w + l * HH * HH; dst = p.ilt + l * HH * HH;  R = HH; C = HH; K = HH; break;
        }
    } else if (j == 18) { src = p.lin1_w; dst = p.l1t; R = HH;  C = H2D; K = HH; }
    else                { src = p.lin2_w; dst = p.l2t; R = H2D; C = H2D; K = H2D; }
    int total = C * K;
    for (int idx = threadIdx.x; idx < total; idx += blockDim.x) {
        int c = idx / K, r = idx - c * K;
        dst[idx] = (r < R) ? (bf16)src[r * C + c] : (bf16)0.f;
    }
}

// -------- filter table: T[l][r][:] = (ssp(gauss(d)@W1+b1)@W2+b2) * C(d) ------
__global__ __launch_bounds__(128) void table_kernel(const float* __restrict__ mlp_w1,
                                                    const float* __restrict__ mlp_b1,
                                                    const float* __restrict__ mlp_w2,
                                                    const float* __restrict__ mlp_b2,
                                                    bf16* __restrict__ tab) {
    int l = blockIdx.x / (NK + 1);
    int r = blockIdx.x % (NK + 1);
    float d = r * (10.f / NK);
    __shared__ float ed[GG];
    __shared__ float h1[FF];
    int f = threadIdx.x;
    const float step = 10.f / 49.f;
    const float coeff = -0.5f / (step * step);
    if (f < GG) {
        float diff = d - f * step;
        ed[f] = __expf(coeff * diff * diff);
    }
    __syncthreads();
    const float* W1 = mlp_w1 + l * GG * FF;
    float s = mlp_b1[l * FF + f];
    for (int g = 0; g < GG; g++) s += ed[g] * W1[g * FF + f];
    h1[f] = sspf(s);
    __syncthreads();
    const float* W2 = mlp_w2 + l * FF * FF;
    float s2 = mlp_b2[l * FF + f];
    for (int j = 0; j < FF; j++) s2 += h1[j] * W2[j * FF + f];
    float Cw = 0.5f * (cosf(d * 0.31415926535897932f) + 1.f);
    tab[((size_t)l * 1026 + r) * FF + f] = (bf16)(s2 * Cw);
}

// -------- edge sort by dst: histogram / hierarchical scan / scatter ----------
__global__ void hist_kernel(const int* __restrict__ eidx, int* __restrict__ hist) {
    int e = blockIdx.x * 256 + threadIdx.x;
    if (e < EE) atomicAdd(&hist[eidx[EE + e]], 1);
}

__global__ __launch_bounds__(256) void scanA_kernel(const int* __restrict__ hist,
                                                    int* __restrict__ bsum) {
    __shared__ int red[256];
    int t = threadIdx.x;
    int i = blockIdx.x * 256 + t;
    int v = (i < NN) ? hist[i] : 0;
    red[t] = v;
    __syncthreads();
    for (int off = 128; off > 0; off >>= 1) {
        if (t < off) red[t] += red[t + off];
        __syncthreads();
    }
    if (t == 0) bsum[blockIdx.x] = red[0];
}

__global__ __launch_bounds__(256) void scanB_kernel(int* __restrict__ bsum) {
    __shared__ int buf[256];
    int t = threadIdx.x;
    int v = (t < SB) ? bsum[t] : 0;
    buf[t] = v;
    __syncthreads();
    for (int off = 1; off < 256; off <<= 1) {
        int y = (t >= off) ? buf[t - off] : 0;
        __syncthreads();
        buf[t] += y;
        __syncthreads();
    }
    if (t < SB) bsum[t] = buf[t] - v;   // exclusive
}

__global__ __launch_bounds__(256) void scanC_kernel(const int* __restrict__ hist,
                                                    const int* __restrict__ bsum,
                                                    int* __restrict__ rs,
                                                    int* __restrict__ cur) {
    __shared__ int buf[256];
    int t = threadIdx.x;
    int i = blockIdx.x * 256 + t;
    int v = (i < NN) ? hist[i] : 0;
    buf[t] = v;
    __syncthreads();
    for (int off = 1; off < 256; off <<= 1) {
        int y = (t >= off) ? buf[t - off] : 0;
        __syncthreads();
        buf[t] += y;
        __syncthreads();
    }
    if (i < NN) {
        int ex = buf[t] - v + bsum[blockIdx.x];
        rs[i] = ex;
        cur[i] = ex;
    }
}

__global__ void scatter_kernel(const float* __restrict__ eattr, const int* __restrict__ eidx,
                               int* __restrict__ cur, int2* __restrict__ es) {
    int e = blockIdx.x * 256 + threadIdx.x;
    if (e < EE) {
        int dd = eidx[EE + e];
        int pos = atomicAdd(&cur[dd], 1);
        int2 v; v.x = __float_as_int(eattr[e]); v.y = eidx[e];
        es[pos] = v;
    }
}

// -------- embed: h = embedding[x_atoms] (f32) --------------------------------
__global__ void embed_kernel(const int* __restrict__ x_atoms, const float* __restrict__ emb,
                             float* __restrict__ h) {
    int idx = blockIdx.x * blockDim.x + threadIdx.x;   // over NN*16
    if (idx >= NN * 16) return;
    int n = idx >> 4, ch = idx & 15;
    int a = x_atoms[n];
    const float* ep = emb + a * HH + ch * 8;
    f32x4 v0 = *(const f32x4*)ep;
    f32x4 v1 = *(const f32x4*)(ep + 4);
    float* hp = h + n * HH + ch * 8;
    *(f32x4*)hp = v0;
    *(f32x4*)(hp + 4) = v1;
}

// -------- xf = h @ conv1_w  (bf16 out, f32 h in) — layer 0 only --------------
__global__ __launch_bounds__(256) void xf_kernel(const float* __restrict__ h,
                                                 const bf16* __restrict__ c1t,
                                                 bf16* __restrict__ xf) {
    __shared__ bf16 sB[128 * 136];
    int tid = threadIdx.x;
    for (int idx = tid * 8; idx < 128 * 128; idx += 2048) {
        int n = idx >> 7, k = idx & 127;
        *(bf16x8*)&sB[n * 136 + k] = *(const bf16x8*)(c1t + idx);
    }
    int w = tid >> 6, lane = tid & 63, ln = lane & 15, kg = lane >> 4;
    int rowt = blockIdx.x * 64 + w * 16;
    int arow = min(rowt + ln, NN - 1);
    __syncthreads();
    f32x4 acc[8] = {};
#pragma unroll
    for (int k0 = 0; k0 < 128; k0 += 32) {
        const float* ap = h + arow * HH + k0 + kg * 8;
        f32x4 u0 = *(const f32x4*)ap;
        f32x4 u1 = *(const f32x4*)(ap + 4);
        bf16x8 a;
#pragma unroll
        for (int q = 0; q < 4; q++) { a[q] = (bf16)u0[q]; a[q + 4] = (bf16)u1[q]; }
#pragma unroll
        for (int t = 0; t < 8; t++) {
            bf16x8 b = *(const bf16x8*)&sB[(t * 16 + ln) * 136 + k0 + kg * 8];
            acc[t] = mfma16(a, b, acc[t]);
        }
    }
#pragma unroll
    for (int t = 0; t < 8; t++) {
        int colt = t * 16 + ln;
#pragma unroll
        for (int r = 0; r < 4; r++) {
            int orow = rowt + kg * 4 + r;
            if (orow < NN) xf[orow * FF + colt] = (bf16)acc[t][r];
        }
    }
}

// -------- fused layer: gather+agg -> conv2 -> int_lin -> (xf_next | head) ----
struct LayerArgs {
    const int2* es; const int* rs; const int* hist;
    const bf16* xf_in; const bf16* tab;
    const bf16* c2t; const float* c2b;
    const bf16* ilt; const float* ilb;
    float* h;
    const bf16* c1n; bf16* xf_out;          // c1n==nullptr => head mode
    const bf16* l1t; const float* l1b; const bf16* l2t; const float* l2b;
    float* partial;
};

__global__ __launch_bounds__(256) void layer_kernel(LayerArgs A) {
    __shared__ bf16 sB[128 * 136];   // 34816 B (restaged per GEMM)
    __shared__ bf16 sT[64 * 136];    // 17408 B (per-wave-private rows)
    int tid = threadIdx.x;
    int w = tid >> 6, lane = tid & 63, ln16 = lane & 15, kg = lane >> 4;
    // stage sB = conv2^T while gathering
    for (int idx = tid * 8; idx < 128 * 128; idx += 2048) {
        int n = idx >> 7, k = idx & 127;
        *(bf16x8*)&sB[n * 136 + k] = *(const bf16x8*)(A.c2t + idx);
    }
    // ---- gather: 16 nodes per wave, f32 agg in regs -> own sT rows (bf16) ---
    int nb = blockIdx.x * 64 + w * 16;
    int startm = 0, degm = 0;
    {
        int nn = nb + ln16;
        if (lane < 16 && nn < NN) { startm = A.rs[nn]; degm = A.hist[nn]; }
    }
    for (int i = 0; i < 16; i++) {
        int start = __shfl(startm, i);
        int deg   = __shfl(degm, i);
        float a0 = 0.f, a1 = 0.f;
        for (int base = 0; base < deg; base += 64) {
            int cnt = min(deg - base, 64);
            float dv = 0.f; int sv = 0;
            if (lane < cnt) {
                int2 es = A.es[start + base + lane];
                dv = __int_as_float(es.x);
                sv = es.y;
            }
            float tt = dv * ((float)NK / 10.f);
            int   kv = (int)tt;
            float fv = tt - (float)kv;
#pragma unroll 4
            for (int j = 0; j < cnt; j++) {
                int   k  = __shfl(kv, j);
                float fr = __shfl(fv, j);
                int   s  = __shfl(sv, j);
                unsigned t0 = *(const unsigned*)(A.tab + k * FF + 2 * lane);
                unsigned t1 = *(const unsigned*)(A.tab + (k + 1) * FF + 2 * lane);
                unsigned xu = *(const unsigned*)(A.xf_in + s * FF + 2 * lane);
                float wa = fmaf(fr, blo(t1) - blo(t0), blo(t0));
                float wb = fmaf(fr, bhi(t1) - bhi(t0), bhi(t0));
                a0 = fmaf(wa, blo(xu), a0);
                a1 = fmaf(wb, bhi(xu), a1);
            }
        }
        bf16x2 pk; pk[0] = (bf16)a0; pk[1] = (bf16)a1;
        *(bf16x2*)&sT[(w * 16 + i) * 136 + 2 * lane] = pk;
    }
    __syncthreads();   // sB staged; sT rows are wave-private (in-order DS pipe)
    // GEMM1: agg @ conv2
    f32x4 acc[8] = {};
#pragma unroll
    for (int k0 = 0; k0 < 128; k0 += 32) {
        bf16x8 a = *(const bf16x8*)&sT[(w * 16 + ln16) * 136 + k0 + kg * 8];
#pragma unroll
        for (int t = 0; t < 8; t++) {
            bf16x8 b = *(const bf16x8*)&sB[(t * 16 + ln16) * 136 + k0 + kg * 8];
            acc[t] = mfma16(a, b, acc[t]);
        }
    }
#pragma unroll
    for (int t = 0; t < 8; t++) {
        int colt = t * 16 + ln16;
        float bb = A.c2b[colt];
#pragma unroll
        for (int r = 0; r < 4; r++)
            sT[(w * 16 + kg * 4 + r) * 136 + colt] = (bf16)sspf(acc[t][r] + bb);
    }
    __syncthreads();   // all GEMM1 sB reads done
    for (int idx = tid * 8; idx < 128 * 128; idx += 2048) {
        int n = idx >> 7, k = idx & 127;
        *(bf16x8*)&sB[n * 136 + k] = *(const bf16x8*)(A.ilt + idx);
    }
    __syncthreads();
    f32x4 acc2[8] = {};
#pragma unroll
    for (int k0 = 0; k0 < 128; k0 += 32) {
        bf16x8 a = *(const bf16x8*)&sT[(w * 16 + ln16) * 136 + k0 + kg * 8];
#pragma unroll
        for (int t = 0; t < 8; t++) {
            bf16x8 b = *(const bf16x8*)&sB[(t * 16 + ln16) * 136 + k0 + kg * 8];
            acc2[t] = mfma16(a, b, acc2[t]);
        }
    }
    int rowt = blockIdx.x * 64 + w * 16;
    bool is_last = (A.c1n == nullptr);
#pragma unroll
    for (int t = 0; t < 8; t++) {
        int colt = t * 16 + ln16;
        float bb = A.ilb[colt];
#pragma unroll
        for (int r = 0; r < 4; r++) {
            int orow = rowt + kg * 4 + r;
            float hn = 0.f;
            if (orow < NN) {
                hn = A.h[orow * HH + colt] + acc2[t][r] + bb;
                if (!is_last) A.h[orow * HH + colt] = hn;
            }
            sT[(w * 16 + kg * 4 + r) * 136 + colt] = (bf16)hn;
        }
    }
    if (!is_last) {
        // fused next-layer xf = h_new @ conv1_next
        __syncthreads();
        for (int idx = tid * 8; idx < 128 * 128; idx += 2048) {
            int n = idx >> 7, k = idx & 127;
            *(bf16x8*)&sB[n * 136 + k] = *(const bf16x8*)(A.c1n + idx);
        }
        __syncthreads();
        f32x4 acc3[8] = {};
#pragma unroll
        for (int k0 = 0; k0 < 128; k0 += 32) {
            bf16x8 a = *(const bf16x8*)&sT[(w * 16 + ln16) * 136 + k0 + kg * 8];
#pragma unroll
            for (int t = 0; t < 8; t++) {
                bf16x8 b = *(const bf16x8*)&sB[(t * 16 + ln16) * 136 + k0 + kg * 8];
                acc3[t] = mfma16(a, b, acc3[t]);
            }
        }
#pragma unroll
        for (int t = 0; t < 8; t++) {
            int colt = t * 16 + ln16;
#pragma unroll
            for (int r = 0; r < 4; r++) {
                int orow = rowt + kg * 4 + r;
                if (orow < NN) A.xf_out[orow * FF + colt] = (bf16)acc3[t][r];
            }
        }
    } else {
        // fused head: ssp(h@lin1+b)@lin2+b, per-block partial sum
        __syncthreads();
        for (int idx = tid * 8; idx < 64 * 128; idx += 2048) {
            int n = idx >> 7, k = idx & 127;
            *(bf16x8*)&sB[n * 136 + k] = *(const bf16x8*)(A.l1t + idx);
        }
        __syncthreads();
        f32x4 acch[4] = {};
#pragma unroll
        for (int k0 = 0; k0 < 128; k0 += 32) {
            bf16x8 a = *(const bf16x8*)&sT[(w * 16 + ln16) * 136 + k0 + kg * 8];
#pragma unroll
            for (int t = 0; t < 4; t++) {
                bf16x8 b = *(const bf16x8*)&sB[(t * 16 + ln16) * 136 + k0 + kg * 8];
                acch[t] = mfma16(a, b, acch[t]);
            }
        }
#pragma unroll
        for (int t = 0; t < 4; t++) {
            int colt = t * 16 + ln16;
            float bb = A.l1b[colt];
#pragma unroll
            for (int r = 0; r < 4; r++)
                sT[(w * 16 + kg * 4 + r) * 136 + colt] = (bf16)sspf(acch[t][r] + bb);
        }
        __syncthreads();
        for (int idx = tid * 8; idx < 64 * 64; idx += 2048) {
            int n = idx >> 6, k = idx & 63;
            *(bf16x8*)&sB[n * 136 + k] = *(const bf16x8*)(A.l2t + idx);
        }
        __syncthreads();
        f32x4 acc2h[4] = {};
#pragma unroll
        for (int k0 = 0; k0 < 64; k0 += 32) {
            bf16x8 a = *(const bf16x8*)&sT[(w * 16 + ln16) * 136 + k0 + kg * 8];
#pragma unroll
            for (int t = 0; t < 4; t++) {
                bf16x8 b = *(const bf16x8*)&sB[(t * 16 + ln16) * 136 + k0 + kg * 8];
                acc2h[t] = mfma16(a, b, acc2h[t]);
            }
        }
        __syncthreads();   // all sT reads done; reuse start of sT as f32 scratch
        float* sPart = (float*)sT;
#pragma unroll
        for (int t = 0; t < 4; t++) {
            int colt = t * 16 + ln16;
            float bb = A.l2b[colt];
            float v = 0.f;
#pragma unroll
            for (int r = 0; r < 4; r++) {
                int orow = rowt + kg * 4 + r;
                if (orow < NN) v += acc2h[t][r] + bb;
            }
            v += __shfl_xor(v, 16);
            v += __shfl_xor(v, 32);
            if (kg == 0) sPart[w * 64 + colt] = v;
        }
        __syncthreads();
        if (tid < 64) {
            float s = sPart[tid] + sPart[64 + tid] + sPart[128 + tid] + sPart[192 + tid];
            A.partial[blockIdx.x * 64 + tid] = s;
        }
    }
}

__global__ __launch_bounds__(64) void final_kernel(const float* __restrict__ partial,
                                                   const float* __restrict__ rw,
                                                   const float* __restrict__ rb,
                                                   float* __restrict__ out) {
    __shared__ float sv[64];
    int j = threadIdx.x;
    float s = 0.f;
    for (int b = 0; b < NBLK; b++) s += partial[b * 64 + j];
    sv[j] = s;
    __syncthreads();
    if (j < OUT_DIM) {
        float o = rb[j];
        for (int i = 0; i < H2D; i++) o += sv[i] * rw[i * OUT_DIM + j];
        out[j] = o;
    }
}

// -------- launch -------------------------------------------------------------
extern "C" void kernel_launch(void* const* d_in, const int* in_sizes, int n_in,
                              void* d_out, int out_size, void* d_ws, size_t ws_size,
                              hipStream_t stream) {
    const int*   x_atoms    = (const int*)d_in[0];
    const int*   edge_index = (const int*)d_in[1];
    const float* edge_attr  = (const float*)d_in[2];
    const float* embedding  = (const float*)d_in[3];
    const float* mlp_w1     = (const float*)d_in[4];
    const float* mlp_b1     = (const float*)d_in[5];
    const float* mlp_w2     = (const float*)d_in[6];
    const float* mlp_b2     = (const float*)d_in[7];
    const float* conv1_w    = (const float*)d_in[8];
    const float* conv2_w    = (const float*)d_in[9];
    const float* conv2_b    = (const float*)d_in[10];
    const float* int_lin_w  = (const float*)d_in[11];
    const float* int_lin_b  = (const float*)d_in[12];
    const float* lin1_w     = (const float*)d_in[13];
    const float* lin1_b     = (const float*)d_in[14];
    const float* lin2_w     = (const float*)d_in[15];
    const float* lin2_b     = (const float*)d_in[16];
    const float* readout_w  = (const float*)d_in[17];
    const float* readout_b  = (const float*)d_in[18];

    char* ws = (char*)d_ws;
    float* h       = (float*)(ws + 0);             // 25,600,000
    bf16*  xfA     = (bf16*)(ws + 25600000);       // 12,800,000
    bf16*  xfB     = (bf16*)(ws + 38400000);       // 12,800,000 -> 51,200,000
    float* partial = (float*)(ws + 64000000);      // 200,192 (782*64*4)
    size_t wb = 64200192;
    bf16* c1t = (bf16*)(ws + wb);                  // 196,608
    bf16* c2t = (bf16*)(ws + wb + 196608);
    bf16* ilt = (bf16*)(ws + wb + 393216);
    bf16* l1t = (bf16*)(ws + wb + 589824);         // 16,384
    bf16* l2t = (bf16*)(ws + wb + 606208);         // 8,192
    // sort scratch (from 64,814,592)
    int*   d_hist = (int*)(ws + 64814592);         // 200,000
    int*   d_rs   = (int*)(ws + 65014592);         // 200,000
    int*   d_cur  = (int*)(ws + 65214592);         // 200,000
    int*   d_bsum = (int*)(ws + 65414592);         // 1,024
    int2*  d_es   = (int2*)(ws + 65415616);        // 6,400,000 -> 71,815,616
    // filter tables: [L][1026][128] bf16 = 1,575,936
    bf16*  tab    = (bf16*)(ws + 71815616);        // ends 73,391,552

    PrepArgs pa = { conv1_w, conv2_w, int_lin_w, lin1_w, lin2_w,
                    c1t, c2t, ilt, l1t, l2t };
    prep_kernel<<<20, 256, 0, stream>>>(pa);
    table_kernel<<<LL * (NK + 1), 128, 0, stream>>>(mlp_w1, mlp_b1, mlp_w2, mlp_b2, tab);
    embed_kernel<<<NN * 16 / 256, 256, 0, stream>>>(x_atoms, embedding, h);

    // sort edges by dst (once; graph static across layers)
    hipMemsetAsync(d_hist, 0, NN * 4, stream);
    hist_kernel<<<(EE + 255) / 256, 256, 0, stream>>>(edge_index, d_hist);
    scanA_kernel<<<SB, 256, 0, stream>>>(d_hist, d_bsum);
    scanB_kernel<<<1, 256, 0, stream>>>(d_bsum);
    scanC_kernel<<<SB, 256, 0, stream>>>(d_hist, d_bsum, d_rs, d_cur);
    scatter_kernel<<<(EE + 255) / 256, 256, 0, stream>>>(edge_attr, edge_index, d_cur, d_es);

    xf_kernel<<<NBLK, 256, 0, stream>>>(h, c1t, xfA);   // layer 0 xf
    bf16* xf_in = xfA;
    bf16* xf_out = xfB;
    for (int l = 0; l < LL; l++) {
        LayerArgs la;
        la.es = d_es; la.rs = d_rs; la.hist = d_hist;
        la.xf_in = xf_in; la.tab = tab + (size_t)l * 1026 * FF;
        la.c2t = c2t + (size_t)l * HH * FF; la.c2b = conv2_b + l * HH;
        la.ilt = ilt + (size_t)l * HH * HH; la.ilb = int_lin_b + l * HH;
        la.h = h;
        la.c1n = (l + 1 < LL) ? (c1t + (size_t)(l + 1) * FF * HH) : nullptr;
        la.xf_out = xf_out;
        la.l1t = l1t; la.l1b = lin1_b; la.l2t = l2t; la.l2b = lin2_b;
        la.partial = partial;
        layer_kernel<<<NBLK, 256, 0, stream>>>(la);
        bf16* tmp = xf_in; xf_in = xf_out; xf_out = tmp;
    }
    final_kernel<<<1, 64, 0, stream>>>(partial, readout_w, readout_b, (float*)d_out);
}

// Round 8
// 803.488 us; speedup vs baseline: 2.1039x; 2.1039x over previous
//
#include <hip/hip_runtime.h>
#include <hip/hip_bf16.h>
#include <math.h>

#define NN 50000
#define EE 800000
#define HH 128
#define FF 128
#define GG 50
#define LL 6
#define H2D 64
#define OUT_DIM 12
#define NK 1024          // table intervals; paired rows r: (T_r, T_{r+1})
#define NBLK 782         // ceil(NN/64)
#define SB 196           // scan blocks: ceil(NN/256)

typedef __bf16 bf16;
typedef __attribute__((ext_vector_type(8))) __bf16 bf16x8;
typedef __attribute__((ext_vector_type(4))) __bf16 bf16x4;
typedef __attribute__((ext_vector_type(4))) float f32x4;
typedef __attribute__((ext_vector_type(4))) unsigned u32x4;
typedef __attribute__((ext_vector_type(2))) unsigned u32x2;

#define DEV __device__ __forceinline__

DEV float sspf(float x) {
    return fmaxf(x, 0.f) + log1pf(__expf(-fabsf(x))) - 0.69314718055994531f;
}

DEV f32x4 mfma16(bf16x8 a, bf16x8 b, f32x4 c) {
    return __builtin_amdgcn_mfma_f32_16x16x32_bf16(a, b, c, 0, 0, 0);
}

DEV float blo(unsigned u) { return __uint_as_float(u << 16); }
DEV float bhi(unsigned u) { return __uint_as_float(u & 0xffff0000u); }

// -------- prep: transpose node-GEMM weights to [n][k] bf16 -------------------
struct PrepArgs {
    const float *conv1_w, *conv2_w, *int_lin_w, *lin1_w, *lin2_w;
    bf16 *c1t, *c2t, *ilt, *l1t, *l2t;
};

__global__ void prep_kernel(PrepArgs p) {
    int j = blockIdx.x;
    const float* src = nullptr; bf16* dst = nullptr; int R = 0, C = 0, K = 0;
    if (j < 18) {
        int l = j / 3, m = j % 3;
        switch (m) {
            case 0: src = p.conv1_w + l * HH * FF;   dst = p.c1t + l * FF * HH;  R = HH; C = FF; K = HH; break;
            case 1: src = p.conv2_w + l * FF * HH;   dst = p.c2t + l * HH * FF;  R = FF; C = HH; K = FF; break;
            case 2: src = p.int_lin_w + l * HH * HH; dst = p.ilt + l * HH * HH;  R = HH; C = HH; K = HH; break;
        }
    } else if (j == 18) { src = p.lin1_w; dst = p.l1t; R = HH;  C = H2D; K = HH; }
    else                { src = p.lin2_w; dst = p.l2t; R = H2D; C = H2D; K = H2D; }
    int total = C * K;
    for (int idx = threadIdx.x; idx < total; idx += blockDim.x) {
        int c = idx / K, r = idx - c * K;
        dst[idx] = (r < R) ? (bf16)src[r * C + c] : (bf16)0.f;
    }
}

// -------- paired filter table: tabP[l][r][c] = (T_r[c], T_{r+1}[c]) ----------
__global__ __launch_bounds__(128) void table_kernel(const float* __restrict__ mlp_w1,
                                                    const float* __restrict__ mlp_b1,
                                                    const float* __restrict__ mlp_w2,
                                                    const float* __restrict__ mlp_b2,
                                                    bf16* __restrict__ tab) {
    int l = blockIdx.x / (NK + 1);
    int r = blockIdx.x % (NK + 1);
    float d = r * (10.f / NK);
    __shared__ float ed[GG];
    __shared__ float h1[FF];
    int f = threadIdx.x;
    const float step = 10.f / 49.f;
    const float coeff = -0.5f / (step * step);
    if (f < GG) {
        float diff = d - f * step;
        ed[f] = __expf(coeff * diff * diff);
    }
    __syncthreads();
    const float* W1 = mlp_w1 + l * GG * FF;
    float s = mlp_b1[l * FF + f];
    for (int g = 0; g < GG; g++) s += ed[g] * W1[g * FF + f];
    h1[f] = sspf(s);
    __syncthreads();
    const float* W2 = mlp_w2 + l * FF * FF;
    float s2 = mlp_b2[l * FF + f];
    for (int j = 0; j < FF; j++) s2 += h1[j] * W2[j * FF + f];
    float Cw = 0.5f * (cosf(d * 0.31415926535897932f) + 1.f);
    bf16 vb = (bf16)(s2 * Cw);
    bf16* base = tab + (size_t)l * NK * 256;   // row: 128 ch x 2 slots
    if (r < NK) base[(size_t)r * 256 + 2 * f] = vb;            // lo slot of row r
    if (r > 0)  base[(size_t)(r - 1) * 256 + 2 * f + 1] = vb;  // hi slot of row r-1
}

// -------- edge sort by dst: histogram / hierarchical scan / scatter ----------
__global__ void hist_kernel(const int* __restrict__ eidx, int* __restrict__ hist) {
    int e = blockIdx.x * 256 + threadIdx.x;
    if (e < EE) atomicAdd(&hist[eidx[EE + e]], 1);
}

__global__ __launch_bounds__(256) void scanA_kernel(const int* __restrict__ hist,
                                                    int* __restrict__ bsum) {
    __shared__ int red[256];
    int t = threadIdx.x;
    int i = blockIdx.x * 256 + t;
    int v = (i < NN) ? hist[i] : 0;
    red[t] = v;
    __syncthreads();
    for (int off = 128; off > 0; off >>= 1) {
        if (t < off) red[t] += red[t + off];
        __syncthreads();
    }
    if (t == 0) bsum[blockIdx.x] = red[0];
}

__global__ __launch_bounds__(256) void scanB_kernel(int* __restrict__ bsum) {
    __shared__ int buf[256];
    int t = threadIdx.x;
    int v = (t < SB) ? bsum[t] : 0;
    buf[t] = v;
    __syncthreads();
    for (int off = 1; off < 256; off <<= 1) {
        int y = (t >= off) ? buf[t - off] : 0;
        __syncthreads();
        buf[t] += y;
        __syncthreads();
    }
    if (t < SB) bsum[t] = buf[t] - v;   // exclusive
}

__global__ __launch_bounds__(256) void scanC_kernel(const int* __restrict__ hist,
                                                    const int* __restrict__ bsum,
                                                    int* __restrict__ rs,
                                                    int* __restrict__ cur) {
    __shared__ int buf[256];
    int t = threadIdx.x;
    int i = blockIdx.x * 256 + t;
    int v = (i < NN) ? hist[i] : 0;
    buf[t] = v;
    __syncthreads();
    for (int off = 1; off < 256; off <<= 1) {
        int y = (t >= off) ? buf[t - off] : 0;
        __syncthreads();
        buf[t] += y;
        __syncthreads();
    }
    if (i < NN) {
        int ex = buf[t] - v + bsum[blockIdx.x];
        rs[i] = ex;
        cur[i] = ex;
    }
}

__global__ void scatter_kernel(const float* __restrict__ eattr, const int* __restrict__ eidx,
                               int* __restrict__ cur, int2* __restrict__ es) {
    int e = blockIdx.x * 256 + threadIdx.x;
    if (e < EE) {
        int dd = eidx[EE + e];
        int pos = atomicAdd(&cur[dd], 1);
        int2 v; v.x = __float_as_int(eattr[e]); v.y = eidx[e];
        es[pos] = v;
    }
}

// -------- embed: hb = embedding[x_atoms] (bf16) ------------------------------
__global__ void embed_kernel(const int* __restrict__ x_atoms, const float* __restrict__ emb,
                             bf16* __restrict__ hb) {
    int idx = blockIdx.x * blockDim.x + threadIdx.x;   // over NN*16
    if (idx >= NN * 16) return;
    int n = idx >> 4, ch = idx & 15;
    int a = x_atoms[n];
    const float* ep = emb + a * HH + ch * 8;
    f32x4 v0 = *(const f32x4*)ep;
    f32x4 v1 = *(const f32x4*)(ep + 4);
    bf16x8 vb;
#pragma unroll
    for (int q = 0; q < 4; q++) { vb[q] = (bf16)v0[q]; vb[q + 4] = (bf16)v1[q]; }
    *(bf16x8*)(hb + n * HH + ch * 8) = vb;
}

// -------- xf = hb @ conv1_w  (layer 0 only) ----------------------------------
__global__ __launch_bounds__(256) void xf_kernel(const bf16* __restrict__ hb,
                                                 const bf16* __restrict__ c1t,
                                                 bf16* __restrict__ xf) {
    __shared__ bf16 sB[128 * 136];
    int tid = threadIdx.x;
    for (int idx = tid * 8; idx < 128 * 128; idx += 2048) {
        int n = idx >> 7, k = idx & 127;
        *(bf16x8*)&sB[n * 136 + k] = *(const bf16x8*)(c1t + idx);
    }
    int w = tid >> 6, lane = tid & 63, ln = lane & 15, kg = lane >> 4;
    int rowt = blockIdx.x * 64 + w * 16;
    int arow = min(rowt + ln, NN - 1);
    __syncthreads();
    f32x4 acc[8] = {};
#pragma unroll
    for (int k0 = 0; k0 < 128; k0 += 32) {
        bf16x8 a = *(const bf16x8*)(hb + arow * HH + k0 + kg * 8);
#pragma unroll
        for (int t = 0; t < 8; t++) {
            bf16x8 b = *(const bf16x8*)&sB[(t * 16 + ln) * 136 + k0 + kg * 8];
            acc[t] = mfma16(a, b, acc[t]);
        }
    }
#pragma unroll
    for (int t = 0; t < 8; t++) {
        int colt = t * 16 + ln;
#pragma unroll
        for (int r = 0; r < 4; r++) {
            int orow = rowt + kg * 4 + r;
            if (orow < NN) xf[orow * FF + colt] = (bf16)acc[t][r];
        }
    }
}

// -------- edge kernel: CSR, one wave/node, 2 edges/iter, bf16 agg out --------
__global__ __launch_bounds__(256) void edge_kernel(const int2* __restrict__ es,
                                                   const int* __restrict__ rs,
                                                   const int* __restrict__ hist,
                                                   const bf16* __restrict__ xf,
                                                   const bf16* __restrict__ tab,
                                                   bf16* __restrict__ aggb) {
    int tid = threadIdx.x;
    int w = tid >> 6, lane = tid & 63;
    int half = lane >> 5, cl = lane & 31;      // half: which edge of the pair
    int n = blockIdx.x * 4 + w;
    int start = rs[n], deg = hist[n];
    float a0 = 0.f, a1 = 0.f, a2 = 0.f, a3 = 0.f;
    for (int base = 0; base < deg; base += 64) {
        int cnt = min(deg - base, 64);
        float dv = 0.f; int sv = 0;
        if (lane < cnt) {
            int2 e = es[start + base + lane];
            dv = __int_as_float(e.x);
            sv = e.y;
        }
        float tt = dv * ((float)NK / 10.f);
        int   kv = min((int)tt, NK - 1);
        float fv = tt - (float)((int)tt);
        int iters = (cnt + 1) >> 1;
#pragma unroll 2
        for (int j = 0; j < iters; j++) {
            int jj = 2 * j + half;
            bool valid = jj < cnt;
            int   k  = __shfl(kv, jj);
            float fr = __shfl(fv, jj);
            int   s  = __shfl(sv, jj);
            u32x4 tp = *(const u32x4*)(tab + (size_t)k * 256 + 8 * cl);
            u32x2 xu = *(const u32x2*)(xf + (size_t)s * FF + 4 * cl);
            float w0 = fmaf(fr, bhi(tp.x) - blo(tp.x), blo(tp.x));
            float w1 = fmaf(fr, bhi(tp.y) - blo(tp.y), blo(tp.y));
            float w2 = fmaf(fr, bhi(tp.z) - blo(tp.z), blo(tp.z));
            float w3 = fmaf(fr, bhi(tp.w) - blo(tp.w), blo(tp.w));
            w0 = valid ? w0 : 0.f;
            w1 = valid ? w1 : 0.f;
            w2 = valid ? w2 : 0.f;
            w3 = valid ? w3 : 0.f;
            a0 = fmaf(w0, blo(xu.x), a0);
            a1 = fmaf(w1, bhi(xu.x), a1);
            a2 = fmaf(w2, blo(xu.y), a2);
            a3 = fmaf(w3, bhi(xu.y), a3);
        }
    }
    a0 += __shfl_xor(a0, 32);
    a1 += __shfl_xor(a1, 32);
    a2 += __shfl_xor(a2, 32);
    a3 += __shfl_xor(a3, 32);
    if (half == 0) {
        bf16x4 pk;
        pk[0] = (bf16)a0; pk[1] = (bf16)a1; pk[2] = (bf16)a2; pk[3] = (bf16)a3;
        *(bf16x4*)(aggb + (size_t)n * FF + 4 * cl) = pk;
    }
}

// -------- update: hb += ssp(aggb@conv2+b)@int_lin+b; then xf_next | head -----
__global__ __launch_bounds__(256) void update_kernel(const bf16* __restrict__ aggb,
                                                     const bf16* __restrict__ c2t,
                                                     const float* __restrict__ c2b,
                                                     const bf16* __restrict__ ilt,
                                                     const float* __restrict__ ilb,
                                                     bf16* __restrict__ hb,
                                                     const bf16* __restrict__ c1n,
                                                     bf16* __restrict__ xf_out,
                                                     const bf16* __restrict__ l1t,
                                                     const float* __restrict__ l1b,
                                                     const bf16* __restrict__ l2t,
                                                     const float* __restrict__ l2b,
                                                     float* __restrict__ partial) {
    __shared__ bf16 sB[128 * 136];   // restaged per GEMM
    __shared__ bf16 sT[64 * 136];
    int tid = threadIdx.x;
    for (int idx = tid * 8; idx < 128 * 128; idx += 2048) {
        int n = idx >> 7, k = idx & 127;
        *(bf16x8*)&sB[n * 136 + k] = *(const bf16x8*)(c2t + idx);
    }
    int w = tid >> 6, lane = tid & 63, ln = lane & 15, kg = lane >> 4;
    int rowt = blockIdx.x * 64 + w * 16;
    int arow = min(rowt + ln, NN - 1);
    __syncthreads();
    // GEMM1: aggb @ conv2 (A direct from global bf16)
    f32x4 acc[8] = {};
#pragma unroll
    for (int k0 = 0; k0 < 128; k0 += 32) {
        bf16x8 a = *(const bf16x8*)(aggb + (size_t)arow * FF + k0 + kg * 8);
#pragma unroll
        for (int t = 0; t < 8; t++) {
            bf16x8 b = *(const bf16x8*)&sB[(t * 16 + ln) * 136 + k0 + kg * 8];
            acc[t] = mfma16(a, b, acc[t]);
        }
    }
#pragma unroll
    for (int t = 0; t < 8; t++) {
        int colt = t * 16 + ln;
        float bb = c2b[colt];
#pragma unroll
        for (int r = 0; r < 4; r++)
            sT[(w * 16 + kg * 4 + r) * 136 + colt] = (bf16)sspf(acc[t][r] + bb);
    }
    __syncthreads();
    for (int idx = tid * 8; idx < 128 * 128; idx += 2048) {
        int n = idx >> 7, k = idx & 127;
        *(bf16x8*)&sB[n * 136 + k] = *(const bf16x8*)(ilt + idx);
    }
    __syncthreads();
    f32x4 acc2[8] = {};
#pragma unroll
    for (int k0 = 0; k0 < 128; k0 += 32) {
        bf16x8 a = *(const bf16x8*)&sT[(w * 16 + ln) * 136 + k0 + kg * 8];
#pragma unroll
        for (int t = 0; t < 8; t++) {
            bf16x8 b = *(const bf16x8*)&sB[(t * 16 + ln) * 136 + k0 + kg * 8];
            acc2[t] = mfma16(a, b, acc2[t]);
        }
    }
    bool is_last = (c1n == nullptr);
#pragma unroll
    for (int t = 0; t < 8; t++) {
        int colt = t * 16 + ln;
        float bb = ilb[colt];
#pragma unroll
        for (int r = 0; r < 4; r++) {
            int orow = rowt + kg * 4 + r;
            float hn = 0.f;
            if (orow < NN) {
                hn = (float)hb[(size_t)orow * HH + colt] + acc2[t][r] + bb;
                if (!is_last) hb[(size_t)orow * HH + colt] = (bf16)hn;
            }
            sT[(w * 16 + kg * 4 + r) * 136 + colt] = (bf16)hn;
        }
    }
    if (!is_last) {
        // fused next-layer xf = h_new @ conv1_next
        __syncthreads();
        for (int idx = tid * 8; idx < 128 * 128; idx += 2048) {
            int n = idx >> 7, k = idx & 127;
            *(bf16x8*)&sB[n * 136 + k] = *(const bf16x8*)(c1n + idx);
        }
        __syncthreads();
        f32x4 acc3[8] = {};
#pragma unroll
        for (int k0 = 0; k0 < 128; k0 += 32) {
            bf16x8 a = *(const bf16x8*)&sT[(w * 16 + ln) * 136 + k0 + kg * 8];
#pragma unroll
            for (int t = 0; t < 8; t++) {
                bf16x8 b = *(const bf16x8*)&sB[(t * 16 + ln) * 136 + k0 + kg * 8];
                acc3[t] = mfma16(a, b, acc3[t]);
            }
        }
#pragma unroll
        for (int t = 0; t < 8; t++) {
            int colt = t * 16 + ln;
#pragma unroll
            for (int r = 0; r < 4; r++) {
                int orow = rowt + kg * 4 + r;
                if (orow < NN) xf_out[(size_t)orow * FF + colt] = (bf16)acc3[t][r];
            }
        }
    } else {
        // fused head: ssp(h@lin1+b)@lin2+b, per-block partial sum
        __syncthreads();
        for (int idx = tid * 8; idx < 64 * 128; idx += 2048) {
            int n = idx >> 7, k = idx & 127;
            *(bf16x8*)&sB[n * 136 + k] = *(const bf16x8*)(l1t + idx);
        }
        __syncthreads();
        f32x4 acch[4] = {};
#pragma unroll
        for (int k0 = 0; k0 < 128; k0 += 32) {
            bf16x8 a = *(const bf16x8*)&sT[(w * 16 + ln) * 136 + k0 + kg * 8];
#pragma unroll
            for (int t = 0; t < 4; t++) {
                bf16x8 b = *(const bf16x8*)&sB[(t * 16 + ln) * 136 + k0 + kg * 8];
                acch[t] = mfma16(a, b, acch[t]);
            }
        }
#pragma unroll
        for (int t = 0; t < 4; t++) {
            int colt = t * 16 + ln;
            float bb = l1b[colt];
#pragma unroll
            for (int r = 0; r < 4; r++)
                sT[(w * 16 + kg * 4 + r) * 136 + colt] = (bf16)sspf(acch[t][r] + bb);
        }
        __syncthreads();
        for (int idx = tid * 8; idx < 64 * 64; idx += 2048) {
            int n = idx >> 6, k = idx & 63;
            *(bf16x8*)&sB[n * 136 + k] = *(const bf16x8*)(l2t + idx);
        }
        __syncthreads();
        f32x4 acc2h[4] = {};
#pragma unroll
        for (int k0 = 0; k0 < 64; k0 += 32) {
            bf16x8 a = *(const bf16x8*)&sT[(w * 16 + ln) * 136 + k0 + kg * 8];
#pragma unroll
            for (int t = 0; t < 4; t++) {
                bf16x8 b = *(const bf16x8*)&sB[(t * 16 + ln) * 136 + k0 + kg * 8];
                acc2h[t] = mfma16(a, b, acc2h[t]);
            }
        }
        __syncthreads();   // all sT reads done; reuse as f32 scratch
        float* sPart = (float*)sT;
#pragma unroll
        for (int t = 0; t < 4; t++) {
            int colt = t * 16 + ln;
            float bb = l2b[colt];
            float v = 0.f;
#pragma unroll
            for (int r = 0; r < 4; r++) {
                int orow = rowt + kg * 4 + r;
                if (orow < NN) v += acc2h[t][r] + bb;
            }
            v += __shfl_xor(v, 16);
            v += __shfl_xor(v, 32);
            if (kg == 0) sPart[w * 64 + colt] = v;
        }
        __syncthreads();
        if (tid < 64) {
            float s = sPart[tid] + sPart[64 + tid] + sPart[128 + tid] + sPart[192 + tid];
            partial[blockIdx.x * 64 + tid] = s;
        }
    }
}

__global__ __launch_bounds__(64) void final_kernel(const float* __restrict__ partial,
                                                   const float* __restrict__ rw,
                                                   const float* __restrict__ rb,
                                                   float* __restrict__ out) {
    __shared__ float sv[64];
    int j = threadIdx.x;
    float s = 0.f;
    for (int b = 0; b < NBLK; b++) s += partial[b * 64 + j];
    sv[j] = s;
    __syncthreads();
    if (j < OUT_DIM) {
        float o = rb[j];
        for (int i = 0; i < H2D; i++) o += sv[i] * rw[i * OUT_DIM + j];
        out[j] = o;
    }
}

// -------- launch -------------------------------------------------------------
extern "C" void kernel_launch(void* const* d_in, const int* in_sizes, int n_in,
                              void* d_out, int out_size, void* d_ws, size_t ws_size,
                              hipStream_t stream) {
    const int*   x_atoms    = (const int*)d_in[0];
    const int*   edge_index = (const int*)d_in[1];
    const float* edge_attr  = (const float*)d_in[2];
    const float* embedding  = (const float*)d_in[3];
    const float* mlp_w1     = (const float*)d_in[4];
    const float* mlp_b1     = (const float*)d_in[5];
    const float* mlp_w2     = (const float*)d_in[6];
    const float* mlp_b2     = (const float*)d_in[7];
    const float* conv1_w    = (const float*)d_in[8];
    const float* conv2_w    = (const float*)d_in[9];
    const float* conv2_b    = (const float*)d_in[10];
    const float* int_lin_w  = (const float*)d_in[11];
    const float* int_lin_b  = (const float*)d_in[12];
    const float* lin1_w     = (const float*)d_in[13];
    const float* lin1_b     = (const float*)d_in[14];
    const float* lin2_w     = (const float*)d_in[15];
    const float* lin2_b     = (const float*)d_in[16];
    const float* readout_w  = (const float*)d_in[17];
    const float* readout_b  = (const float*)d_in[18];

    char* ws = (char*)d_ws;
    bf16*  hb      = (bf16*)(ws + 0);              // 12,800,000
    bf16*  xfA     = (bf16*)(ws + 12800000);       // 12,800,000
    bf16*  xfB     = (bf16*)(ws + 25600000);       // 12,800,000
    bf16*  aggb    = (bf16*)(ws + 38400000);       // 12,800,000
    float* partial = (float*)(ws + 51200000);      // 200,192
    size_t wb = 51400192;
    bf16* c1t = (bf16*)(ws + wb);                  // 196,608
    bf16* c2t = (bf16*)(ws + wb + 196608);
    bf16* ilt = (bf16*)(ws + wb + 393216);
    bf16* l1t = (bf16*)(ws + wb + 589824);         // 16,384
    bf16* l2t = (bf16*)(ws + wb + 606208);         // 8,192 -> ends 52,014,592
    int*   d_hist = (int*)(ws + 52014592);         // 200,000
    int*   d_rs   = (int*)(ws + 52214592);         // 200,000
    int*   d_cur  = (int*)(ws + 52414592);         // 200,000
    int*   d_bsum = (int*)(ws + 52614592);         // 1,024
    int2*  d_es   = (int2*)(ws + 52615616);        // 6,400,000 -> 59,015,616
    bf16*  tabP   = (bf16*)(ws + 59015616);        // 6*1024*256*2 = 3,145,728 -> 62,161,344

    PrepArgs pa = { conv1_w, conv2_w, int_lin_w, lin1_w, lin2_w,
                    c1t, c2t, ilt, l1t, l2t };
    prep_kernel<<<20, 256, 0, stream>>>(pa);
    table_kernel<<<LL * (NK + 1), 128, 0, stream>>>(mlp_w1, mlp_b1, mlp_w2, mlp_b2, tabP);
    embed_kernel<<<NN * 16 / 256, 256, 0, stream>>>(x_atoms, embedding, hb);

    // sort edges by dst (once; graph static across layers)
    hipMemsetAsync(d_hist, 0, NN * 4, stream);
    hist_kernel<<<(EE + 255) / 256, 256, 0, stream>>>(edge_index, d_hist);
    scanA_kernel<<<SB, 256, 0, stream>>>(d_hist, d_bsum);
    scanB_kernel<<<1, 256, 0, stream>>>(d_bsum);
    scanC_kernel<<<SB, 256, 0, stream>>>(d_hist, d_bsum, d_rs, d_cur);
    scatter_kernel<<<(EE + 255) / 256, 256, 0, stream>>>(edge_attr, edge_index, d_cur, d_es);

    xf_kernel<<<NBLK, 256, 0, stream>>>(hb, c1t, xfA);   // layer 0 xf
    bf16* xf_in = xfA;
    bf16* xf_out = xfB;
    for (int l = 0; l < LL; l++) {
        edge_kernel<<<NN / 4, 256, 0, stream>>>(d_es, d_rs, d_hist, xf_in,
                                                tabP + (size_t)l * NK * 256, aggb);
        const bf16* c1n = (l + 1 < LL) ? (c1t + (size_t)(l + 1) * FF * HH) : nullptr;
        update_kernel<<<NBLK, 256, 0, stream>>>(aggb, c2t + (size_t)l * HH * FF,
                                                conv2_b + l * HH,
                                                ilt + (size_t)l * HH * HH, int_lin_b + l * HH,
                                                hb, c1n, xf_out,
                                                l1t, lin1_b, l2t, lin2_b, partial);
        bf16* tmp = xf_in; xf_in = xf_out; xf_out = tmp;
    }
    final_kernel<<<1, 64, 0, stream>>>(partial, readout_w, readout_b, (float*)d_out);
}

// Round 9
// 786.895 us; speedup vs baseline: 2.1482x; 1.0211x over previous
//
#include <hip/hip_runtime.h>
#include <hip/hip_bf16.h>
#include <math.h>

#define NN 50000
#define EE 800000
#define HH 128
#define FF 128
#define GG 50
#define LL 6
#define H2D 64
#define OUT_DIM 12
#define NK 4096          // nearest-neighbor table intervals; knots 0..NK (4097)
#define NBLK 782         // ceil(NN/64)
#define SB 196           // scan blocks: ceil(NN/256)

typedef __bf16 bf16;
typedef __attribute__((ext_vector_type(8))) __bf16 bf16x8;
typedef __attribute__((ext_vector_type(4))) __bf16 bf16x4;
typedef __attribute__((ext_vector_type(4))) float f32x4;
typedef __attribute__((ext_vector_type(2))) unsigned u32x2;

#define DEV __device__ __forceinline__

DEV float sspf(float x) {
    return fmaxf(x, 0.f) + log1pf(__expf(-fabsf(x))) - 0.69314718055994531f;
}

DEV f32x4 mfma16(bf16x8 a, bf16x8 b, f32x4 c) {
    return __builtin_amdgcn_mfma_f32_16x16x32_bf16(a, b, c, 0, 0, 0);
}

DEV float blo(unsigned u) { return __uint_as_float(u << 16); }
DEV float bhi(unsigned u) { return __uint_as_float(u & 0xffff0000u); }

// -------- prep: transpose all weights to [n][k] bf16 -------------------------
struct PrepArgs {
    const float *conv1_w, *conv2_w, *int_lin_w, *mlp_w1, *mlp_w2, *lin1_w, *lin2_w;
    bf16 *c1t, *c2t, *ilt, *w1t, *w2t, *l1t, *l2t;
};

__global__ void prep_kernel(PrepArgs p) {
    int j = blockIdx.x;
    const float* src = nullptr; bf16* dst = nullptr; int R = 0, C = 0, K = 0;
    if (j < 30) {
        int l = j / 5, m = j % 5;
        switch (m) {
            case 0: src = p.conv1_w + l * HH * FF;   dst = p.c1t + l * FF * HH;  R = HH; C = FF; K = HH; break;
            case 1: src = p.conv2_w + l * FF * HH;   dst = p.c2t + l * HH * FF;  R = FF; C = HH; K = FF; break;
            case 2: src = p.int_lin_w + l * HH * HH; dst = p.ilt + l * HH * HH;  R = HH; C = HH; K = HH; break;
            case 3: src = p.mlp_w1 + l * GG * FF;    dst = p.w1t + l * FF * 64;  R = GG; C = FF; K = 64; break;
            case 4: src = p.mlp_w2 + l * FF * FF;    dst = p.w2t + l * FF * FF;  R = FF; C = FF; K = FF; break;
        }
    } else if (j == 30) { src = p.lin1_w; dst = p.l1t; R = HH;  C = H2D; K = HH; }
    else                { src = p.lin2_w; dst = p.l2t; R = H2D; C = H2D; K = H2D; }
    int total = C * K;
    for (int idx = threadIdx.x; idx < total; idx += blockDim.x) {
        int c = idx / K, r = idx - c * K;
        dst[idx] = (r < R) ? (bf16)src[r * C + c] : (bf16)0.f;
    }
}

// -------- table build via MFMA: T[l][r][:] = (ssp(g(d)@W1+b1)@W2+b2)*C(d) ----
__global__ __launch_bounds__(256) void table_kernel(const bf16* __restrict__ w1t,
                                                    const bf16* __restrict__ w2t,
                                                    const float* __restrict__ mlp_b1,
                                                    const float* __restrict__ mlp_b2,
                                                    bf16* __restrict__ tab) {
    __shared__ bf16 sW1[128 * 72];
    __shared__ bf16 sW2[128 * 136];
    __shared__ bf16 sT1[64 * 136];
    int tid = threadIdx.x;
    int l = blockIdx.x / 65, rb = blockIdx.x % 65;
    const bf16* W1 = w1t + (size_t)l * 128 * 64;
    const bf16* W2 = w2t + (size_t)l * 128 * 128;
    for (int idx = tid * 8; idx < 128 * 64; idx += 2048) {
        int n = idx >> 6, k = idx & 63;
        *(bf16x8*)&sW1[n * 72 + k] = *(const bf16x8*)(W1 + idx);
    }
    for (int idx = tid * 8; idx < 128 * 128; idx += 2048) {
        int n = idx >> 7, k = idx & 127;
        *(bf16x8*)&sW2[n * 136 + k] = *(const bf16x8*)(W2 + idx);
    }
    int w = tid >> 6, lane = tid & 63, ln = lane & 15, kg = lane >> 4;
    int rowt = rb * 64 + w * 16;
    float d1 = (float)min(rowt + ln, NK) * (10.f / NK);
    const float step = 10.f / 49.f;
    const float coeff = -0.5f / (step * step);
    __syncthreads();
    // GEMM1: in-register gaussian basis @ W1
    f32x4 acc[8] = {};
#pragma unroll
    for (int k0 = 0; k0 < 64; k0 += 32) {
        bf16x8 a;
#pragma unroll
        for (int jj = 0; jj < 8; jj++) {
            int g = k0 + kg * 8 + jj;
            float diff = d1 - g * step;
            float v = (g < GG) ? __expf(coeff * diff * diff) : 0.f;
            a[jj] = (bf16)v;
        }
#pragma unroll
        for (int t = 0; t < 8; t++) {
            bf16x8 b = *(const bf16x8*)&sW1[(t * 16 + ln) * 72 + k0 + kg * 8];
            acc[t] = mfma16(a, b, acc[t]);
        }
    }
    const float* b1 = mlp_b1 + l * FF;
#pragma unroll
    for (int t = 0; t < 8; t++) {
        int colt = t * 16 + ln;
        float bb = b1[colt];
#pragma unroll
        for (int r = 0; r < 4; r++)
            sT1[(w * 16 + kg * 4 + r) * 136 + colt] = (bf16)sspf(acc[t][r] + bb);
    }
    __syncthreads();
    f32x4 acc2[8] = {};
#pragma unroll
    for (int k0 = 0; k0 < 128; k0 += 32) {
        bf16x8 a = *(const bf16x8*)&sT1[(w * 16 + ln) * 136 + k0 + kg * 8];
#pragma unroll
        for (int t = 0; t < 8; t++) {
            bf16x8 b = *(const bf16x8*)&sW2[(t * 16 + ln) * 136 + k0 + kg * 8];
            acc2[t] = mfma16(a, b, acc2[t]);
        }
    }
    const float* b2 = mlp_b2 + l * FF;
    float Cw[4]; int rrow[4];
#pragma unroll
    for (int r = 0; r < 4; r++) {
        int rr = rowt + kg * 4 + r;
        rrow[r] = rr;
        float dd = (float)min(rr, NK) * (10.f / NK);
        Cw[r] = 0.5f * (cosf(dd * 0.31415926535897932f) + 1.f);
    }
#pragma unroll
    for (int t = 0; t < 8; t++) {
        int colt = t * 16 + ln;
        float bb = b2[colt];
#pragma unroll
        for (int r = 0; r < 4; r++) {
            if (rrow[r] <= NK)
                tab[((size_t)l * (NK + 1) + rrow[r]) * FF + colt] = (bf16)((acc2[t][r] + bb) * Cw[r]);
        }
    }
}

// -------- edge sort by dst: histogram / hierarchical scan / scatter ----------
__global__ void hist_kernel(const int* __restrict__ eidx, int* __restrict__ hist) {
    int e = blockIdx.x * 256 + threadIdx.x;
    if (e < EE) atomicAdd(&hist[eidx[EE + e]], 1);
}

__global__ __launch_bounds__(256) void scanA_kernel(const int* __restrict__ hist,
                                                    int* __restrict__ bsum) {
    __shared__ int red[256];
    int t = threadIdx.x;
    int i = blockIdx.x * 256 + t;
    int v = (i < NN) ? hist[i] : 0;
    red[t] = v;
    __syncthreads();
    for (int off = 128; off > 0; off >>= 1) {
        if (t < off) red[t] += red[t + off];
        __syncthreads();
    }
    if (t == 0) bsum[blockIdx.x] = red[0];
}

__global__ __launch_bounds__(256) void scanB_kernel(int* __restrict__ bsum) {
    __shared__ int buf[256];
    int t = threadIdx.x;
    int v = (t < SB) ? bsum[t] : 0;
    buf[t] = v;
    __syncthreads();
    for (int off = 1; off < 256; off <<= 1) {
        int y = (t >= off) ? buf[t - off] : 0;
        __syncthreads();
        buf[t] += y;
        __syncthreads();
    }
    if (t < SB) bsum[t] = buf[t] - v;   // exclusive
}

__global__ __launch_bounds__(256) void scanC_kernel(const int* __restrict__ hist,
                                                    const int* __restrict__ bsum,
                                                    int* __restrict__ rs,
                                                    int* __restrict__ cur) {
    __shared__ int buf[256];
    int t = threadIdx.x;
    int i = blockIdx.x * 256 + t;
    int v = (i < NN) ? hist[i] : 0;
    buf[t] = v;
    __syncthreads();
    for (int off = 1; off < 256; off <<= 1) {
        int y = (t >= off) ? buf[t - off] : 0;
        __syncthreads();
        buf[t] += y;
        __syncthreads();
    }
    if (i < NN) {
        int ex = buf[t] - v + bsum[blockIdx.x];
        rs[i] = ex;
        cur[i] = ex;
    }
}

// pack (knot index | src<<13) — 4 B per edge
__global__ void scatter_kernel(const float* __restrict__ eattr, const int* __restrict__ eidx,
                               int* __restrict__ cur, int* __restrict__ es) {
    int e = blockIdx.x * 256 + threadIdx.x;
    if (e < EE) {
        int dd = eidx[EE + e];
        int pos = atomicAdd(&cur[dd], 1);
        int k = (int)(eattr[e] * ((float)NK / 10.f) + 0.5f);
        k = min(k, NK);
        es[pos] = k | (eidx[e] << 13);
    }
}

// -------- embed: hb = embedding[x_atoms] (bf16) ------------------------------
__global__ void embed_kernel(const int* __restrict__ x_atoms, const float* __restrict__ emb,
                             bf16* __restrict__ hb) {
    int idx = blockIdx.x * blockDim.x + threadIdx.x;   // over NN*16
    if (idx >= NN * 16) return;
    int n = idx >> 4, ch = idx & 15;
    int a = x_atoms[n];
    const float* ep = emb + a * HH + ch * 8;
    f32x4 v0 = *(const f32x4*)ep;
    f32x4 v1 = *(const f32x4*)(ep + 4);
    bf16x8 vb;
#pragma unroll
    for (int q = 0; q < 4; q++) { vb[q] = (bf16)v0[q]; vb[q + 4] = (bf16)v1[q]; }
    *(bf16x8*)(hb + n * HH + ch * 8) = vb;
}

// -------- xf = hb @ conv1_w  (layer 0 only) ----------------------------------
__global__ __launch_bounds__(256) void xf_kernel(const bf16* __restrict__ hb,
                                                 const bf16* __restrict__ c1t,
                                                 bf16* __restrict__ xf) {
    __shared__ bf16 sB[128 * 136];
    int tid = threadIdx.x;
    for (int idx = tid * 8; idx < 128 * 128; idx += 2048) {
        int n = idx >> 7, k = idx & 127;
        *(bf16x8*)&sB[n * 136 + k] = *(const bf16x8*)(c1t + idx);
    }
    int w = tid >> 6, lane = tid & 63, ln = lane & 15, kg = lane >> 4;
    int rowt = blockIdx.x * 64 + w * 16;
    int arow = min(rowt + ln, NN - 1);
    __syncthreads();
    f32x4 acc[8] = {};
#pragma unroll
    for (int k0 = 0; k0 < 128; k0 += 32) {
        bf16x8 a = *(const bf16x8*)(hb + arow * HH + k0 + kg * 8);
#pragma unroll
        for (int t = 0; t < 8; t++) {
            bf16x8 b = *(const bf16x8*)&sB[(t * 16 + ln) * 136 + k0 + kg * 8];
            acc[t] = mfma16(a, b, acc[t]);
        }
    }
#pragma unroll
    for (int t = 0; t < 8; t++) {
        int colt = t * 16 + ln;
#pragma unroll
        for (int r = 0; r < 4; r++) {
            int orow = rowt + kg * 4 + r;
            if (orow < NN) xf[orow * FF + colt] = (bf16)acc[t][r];
        }
    }
}

// -------- edge kernel: CSR, one wave/node, nearest-knot, 2 edges/iter --------
__global__ __launch_bounds__(256) void edge_kernel(const int* __restrict__ es,
                                                   const int* __restrict__ rs,
                                                   const int* __restrict__ hist,
                                                   const bf16* __restrict__ xf,
                                                   const bf16* __restrict__ tab,
                                                   bf16* __restrict__ aggb) {
    int tid = threadIdx.x;
    int w = tid >> 6, lane = tid & 63;
    int half = lane >> 5, cl = lane & 31;      // half: which edge of the pair
    int n = blockIdx.x * 4 + w;
    int start = rs[n], deg = hist[n];
    float a0 = 0.f, a1 = 0.f, a2 = 0.f, a3 = 0.f;
    for (int base = 0; base < deg; base += 64) {
        int cnt = min(deg - base, 64);
        int pv = (lane < cnt) ? es[start + base + lane] : 0;
        int iters = (cnt + 1) >> 1;
#pragma unroll 2
        for (int j = 0; j < iters; j++) {
            int jj = 2 * j + half;
            bool valid = jj < cnt;
            int v = __shfl(pv, jj);
            int k = v & 8191;
            int s = v >> 13;
            u32x2 tp = *(const u32x2*)(tab + (size_t)k * FF + 4 * cl);
            u32x2 xu = *(const u32x2*)(xf + (size_t)s * FF + 4 * cl);
            unsigned tx = valid ? tp.x : 0u;
            unsigned ty = valid ? tp.y : 0u;
            a0 = fmaf(blo(tx), blo(xu.x), a0);
            a1 = fmaf(bhi(tx), bhi(xu.x), a1);
            a2 = fmaf(blo(ty), blo(xu.y), a2);
            a3 = fmaf(bhi(ty), bhi(xu.y), a3);
        }
    }
    a0 += __shfl_xor(a0, 32);
    a1 += __shfl_xor(a1, 32);
    a2 += __shfl_xor(a2, 32);
    a3 += __shfl_xor(a3, 32);
    if (half == 0) {
        bf16x4 pk;
        pk[0] = (bf16)a0; pk[1] = (bf16)a1; pk[2] = (bf16)a2; pk[3] = (bf16)a3;
        *(bf16x4*)(aggb + (size_t)n * FF + 4 * cl) = pk;
    }
}

// -------- update: hb += ssp(aggb@conv2+b)@int_lin+b; then xf_next | head -----
__global__ __launch_bounds__(256) void update_kernel(const bf16* __restrict__ aggb,
                                                     const bf16* __restrict__ c2t,
                                                     const float* __restrict__ c2b,
                                                     const bf16* __restrict__ ilt,
                                                     const float* __restrict__ ilb,
                                                     bf16* __restrict__ hb,
                                                     const bf16* __restrict__ c1n,
                                                     bf16* __restrict__ xf_out,
                                                     const bf16* __restrict__ l1t,
                                                     const float* __restrict__ l1b,
                                                     const bf16* __restrict__ l2t,
                                                     const float* __restrict__ l2b,
                                                     float* __restrict__ partial) {
    __shared__ bf16 sB[128 * 136];   // restaged per GEMM
    __shared__ bf16 sT[64 * 136];
    int tid = threadIdx.x;
    for (int idx = tid * 8; idx < 128 * 128; idx += 2048) {
        int n = idx >> 7, k = idx & 127;
        *(bf16x8*)&sB[n * 136 + k] = *(const bf16x8*)(c2t + idx);
    }
    int w = tid >> 6, lane = tid & 63, ln = lane & 15, kg = lane >> 4;
    int rowt = blockIdx.x * 64 + w * 16;
    int arow = min(rowt + ln, NN - 1);
    __syncthreads();
    // GEMM1: aggb @ conv2 (A direct from global bf16)
    f32x4 acc[8] = {};
#pragma unroll
    for (int k0 = 0; k0 < 128; k0 += 32) {
        bf16x8 a = *(const bf16x8*)(aggb + (size_t)arow * FF + k0 + kg * 8);
#pragma unroll
        for (int t = 0; t < 8; t++) {
            bf16x8 b = *(const bf16x8*)&sB[(t * 16 + ln) * 136 + k0 + kg * 8];
            acc[t] = mfma16(a, b, acc[t]);
        }
    }
#pragma unroll
    for (int t = 0; t < 8; t++) {
        int colt = t * 16 + ln;
        float bb = c2b[colt];
#pragma unroll
        for (int r = 0; r < 4; r++)
            sT[(w * 16 + kg * 4 + r) * 136 + colt] = (bf16)sspf(acc[t][r] + bb);
    }
    __syncthreads();
    for (int idx = tid * 8; idx < 128 * 128; idx += 2048) {
        int n = idx >> 7, k = idx & 127;
        *(bf16x8*)&sB[n * 136 + k] = *(const bf16x8*)(ilt + idx);
    }
    __syncthreads();
    f32x4 acc2[8] = {};
#pragma unroll
    for (int k0 = 0; k0 < 128; k0 += 32) {
        bf16x8 a = *(const bf16x8*)&sT[(w * 16 + ln) * 136 + k0 + kg * 8];
#pragma unroll
        for (int t = 0; t < 8; t++) {
            bf16x8 b = *(const bf16x8*)&sB[(t * 16 + ln) * 136 + k0 + kg * 8];
            acc2[t] = mfma16(a, b, acc2[t]);
        }
    }
    bool is_last = (c1n == nullptr);
#pragma unroll
    for (int t = 0; t < 8; t++) {
        int colt = t * 16 + ln;
        float bb = ilb[colt];
#pragma unroll
        for (int r = 0; r < 4; r++) {
            int orow = rowt + kg * 4 + r;
            float hn = 0.f;
            if (orow < NN) {
                hn = (float)hb[(size_t)orow * HH + colt] + acc2[t][r] + bb;
                if (!is_last) hb[(size_t)orow * HH + colt] = (bf16)hn;
            }
            sT[(w * 16 + kg * 4 + r) * 136 + colt] = (bf16)hn;
        }
    }
    if (!is_last) {
        // fused next-layer xf = h_new @ conv1_next
        __syncthreads();
        for (int idx = tid * 8; idx < 128 * 128; idx += 2048) {
            int n = idx >> 7, k = idx & 127;
            *(bf16x8*)&sB[n * 136 + k] = *(const bf16x8*)(c1n + idx);
        }
        __syncthreads();
        f32x4 acc3[8] = {};
#pragma unroll
        for (int k0 = 0; k0 < 128; k0 += 32) {
            bf16x8 a = *(const bf16x8*)&sT[(w * 16 + ln) * 136 + k0 + kg * 8];
#pragma unroll
            for (int t = 0; t < 8; t++) {
                bf16x8 b = *(const bf16x8*)&sB[(t * 16 + ln) * 136 + k0 + kg * 8];
                acc3[t] = mfma16(a, b, acc3[t]);
            }
        }
#pragma unroll
        for (int t = 0; t < 8; t++) {
            int colt = t * 16 + ln;
#pragma unroll
            for (int r = 0; r < 4; r++) {
                int orow = rowt + kg * 4 + r;
                if (orow < NN) xf_out[(size_t)orow * FF + colt] = (bf16)acc3[t][r];
            }
        }
    } else {
        // fused head: ssp(h@lin1+b)@lin2+b, per-block partial sum
        __syncthreads();
        for (int idx = tid * 8; idx < 64 * 128; idx += 2048) {
            int n = idx >> 7, k = idx & 127;
            *(bf16x8*)&sB[n * 136 + k] = *(const bf16x8*)(l1t + idx);
        }
        __syncthreads();
        f32x4 acch[4] = {};
#pragma unroll
        for (int k0 = 0; k0 < 128; k0 += 32) {
            bf16x8 a = *(const bf16x8*)&sT[(w * 16 + ln) * 136 + k0 + kg * 8];
#pragma unroll
            for (int t = 0; t < 4; t++) {
                bf16x8 b = *(const bf16x8*)&sB[(t * 16 + ln) * 136 + k0 + kg * 8];
                acch[t] = mfma16(a, b, acch[t]);
            }
        }
#pragma unroll
        for (int t = 0; t < 4; t++) {
            int colt = t * 16 + ln;
            float bb = l1b[colt];
#pragma unroll
            for (int r = 0; r < 4; r++)
                sT[(w * 16 + kg * 4 + r) * 136 + colt] = (bf16)sspf(acch[t][r] + bb);
        }
        __syncthreads();
        for (int idx = tid * 8; idx < 64 * 64; idx += 2048) {
            int n = idx >> 6, k = idx & 63;
            *(bf16x8*)&sB[n * 136 + k] = *(const bf16x8*)(l2t + idx);
        }
        __syncthreads();
        f32x4 acc2h[4] = {};
#pragma unroll
        for (int k0 = 0; k0 < 64; k0 += 32) {
            bf16x8 a = *(const bf16x8*)&sT[(w * 16 + ln) * 136 + k0 + kg * 8];
#pragma unroll
            for (int t = 0; t < 4; t++) {
                bf16x8 b = *(const bf16x8*)&sB[(t * 16 + ln) * 136 + k0 + kg * 8];
                acc2h[t] = mfma16(a, b, acc2h[t]);
            }
        }
        __syncthreads();   // all sT reads done; reuse as f32 scratch
        float* sPart = (float*)sT;
#pragma unroll
        for (int t = 0; t < 4; t++) {
            int colt = t * 16 + ln;
            float bb = l2b[colt];
            float v = 0.f;
#pragma unroll
            for (int r = 0; r < 4; r++) {
                int orow = rowt + kg * 4 + r;
                if (orow < NN) v += acc2h[t][r] + bb;
            }
            v += __shfl_xor(v, 16);
            v += __shfl_xor(v, 32);
            if (kg == 0) sPart[w * 64 + colt] = v;
        }
        __syncthreads();
        if (tid < 64) {
            float s = sPart[tid] + sPart[64 + tid] + sPart[128 + tid] + sPart[192 + tid];
            partial[blockIdx.x * 64 + tid] = s;
        }
    }
}

__global__ __launch_bounds__(64) void final_kernel(const float* __restrict__ partial,
                                                   const float* __restrict__ rw,
                                                   const float* __restrict__ rb,
                                                   float* __restrict__ out) {
    __shared__ float sv[64];
    int j = threadIdx.x;
    float s = 0.f;
    for (int b = 0; b < NBLK; b++) s += partial[b * 64 + j];
    sv[j] = s;
    __syncthreads();
    if (j < OUT_DIM) {
        float o = rb[j];
        for (int i = 0; i < H2D; i++) o += sv[i] * rw[i * OUT_DIM + j];
        out[j] = o;
    }
}

// -------- launch -------------------------------------------------------------
extern "C" void kernel_launch(void* const* d_in, const int* in_sizes, int n_in,
                              void* d_out, int out_size, void* d_ws, size_t ws_size,
                              hipStream_t stream) {
    const int*   x_atoms    = (const int*)d_in[0];
    const int*   edge_index = (const int*)d_in[1];
    const float* edge_attr  = (const float*)d_in[2];
    const float* embedding  = (const float*)d_in[3];
    const float* mlp_w1     = (const float*)d_in[4];
    const float* mlp_b1     = (const float*)d_in[5];
    const float* mlp_w2     = (const float*)d_in[6];
    const float* mlp_b2     = (const float*)d_in[7];
    const float* conv1_w    = (const float*)d_in[8];
    const float* conv2_w    = (const float*)d_in[9];
    const float* conv2_b    = (const float*)d_in[10];
    const float* int_lin_w  = (const float*)d_in[11];
    const float* int_lin_b  = (const float*)d_in[12];
    const float* lin1_w     = (const float*)d_in[13];
    const float* lin1_b     = (const float*)d_in[14];
    const float* lin2_w     = (const float*)d_in[15];
    const float* lin2_b     = (const float*)d_in[16];
    const float* readout_w  = (const float*)d_in[17];
    const float* readout_b  = (const float*)d_in[18];

    char* ws = (char*)d_ws;
    bf16*  hb      = (bf16*)(ws + 0);              // 12,800,000
    bf16*  xfA     = (bf16*)(ws + 12800000);       // 12,800,000
    bf16*  xfB     = (bf16*)(ws + 25600000);       // 12,800,000
    bf16*  aggb    = (bf16*)(ws + 38400000);       // 12,800,000
    float* partial = (float*)(ws + 51200000);      // 200,192
    size_t wb = 51400192;
    bf16* c1t = (bf16*)(ws + wb);                  // 196,608
    bf16* c2t = (bf16*)(ws + wb + 196608);
    bf16* ilt = (bf16*)(ws + wb + 393216);
    bf16* w1t = (bf16*)(ws + wb + 589824);         // 98,304
    bf16* w2t = (bf16*)(ws + wb + 688128);         // 196,608
    bf16* l1t = (bf16*)(ws + wb + 884736);         // 16,384
    bf16* l2t = (bf16*)(ws + wb + 901120);         // 8,192 -> ends 52,309,504
    int*   d_hist = (int*)(ws + 52309504);         // 200,000
    int*   d_rs   = (int*)(ws + 52509504);         // 200,000
    int*   d_cur  = (int*)(ws + 52709504);         // 200,000
    int*   d_bsum = (int*)(ws + 52909504);         // 1,024
    int*   d_es   = (int*)(ws + 52910528);         // 3,200,000 -> 56,110,528
    bf16*  tab    = (bf16*)(ws + 56110528);        // 6*4097*128*2 = 6,292,992 -> 62,403,520

    PrepArgs pa = { conv1_w, conv2_w, int_lin_w, mlp_w1, mlp_w2, lin1_w, lin2_w,
                    c1t, c2t, ilt, w1t, w2t, l1t, l2t };
    prep_kernel<<<32, 256, 0, stream>>>(pa);
    table_kernel<<<LL * 65, 256, 0, stream>>>(w1t, w2t, mlp_b1, mlp_b2, tab);
    embed_kernel<<<NN * 16 / 256, 256, 0, stream>>>(x_atoms, embedding, hb);

    // sort edges by dst (once; graph static across layers)
    hipMemsetAsync(d_hist, 0, NN * 4, stream);
    hist_kernel<<<(EE + 255) / 256, 256, 0, stream>>>(edge_index, d_hist);
    scanA_kernel<<<SB, 256, 0, stream>>>(d_hist, d_bsum);
    scanB_kernel<<<1, 256, 0, stream>>>(d_bsum);
    scanC_kernel<<<SB, 256, 0, stream>>>(d_hist, d_bsum, d_rs, d_cur);
    scatter_kernel<<<(EE + 255) / 256, 256, 0, stream>>>(edge_attr, edge_index, d_cur, d_es);

    xf_kernel<<<NBLK, 256, 0, stream>>>(hb, c1t, xfA);   // layer 0 xf
    bf16* xf_in = xfA;
    bf16* xf_out = xfB;
    for (int l = 0; l < LL; l++) {
        edge_kernel<<<NN / 4, 256, 0, stream>>>(d_es, d_rs, d_hist, xf_in,
                                                tab + (size_t)l * (NK + 1) * FF, aggb);
        const bf16* c1n = (l + 1 < LL) ? (c1t + (size_t)(l + 1) * FF * HH) : nullptr;
        update_kernel<<<NBLK, 256, 0, stream>>>(aggb, c2t + (size_t)l * HH * FF,
                                                conv2_b + l * HH,
                                                ilt + (size_t)l * HH * HH, int_lin_b + l * HH,
                                                hb, c1n, xf_out,
                                                l1t, lin1_b, l2t, lin2_b, partial);
        bf16* tmp = xf_in; xf_in = xf_out; xf_out = tmp;
    }
    final_kernel<<<1, 64, 0, stream>>>(partial, readout_w, readout_b, (float*)d_out);
}

// Round 10
// 654.570 us; speedup vs baseline: 2.5825x; 1.2022x over previous
//
#include <hip/hip_runtime.h>
#include <hip/hip_bf16.h>
#include <math.h>

#define NN 50000
#define EE 800000
#define HH 128
#define FF 128
#define GG 50
#define LL 6
#define H2D 64
#define OUT_DIM 12
#define NK 4096          // nearest-neighbor table intervals; knots 0..NK (4097)
#define NBLK 782         // ceil(NN/64)
#define SB 196           // scan blocks: ceil(NN/256)

typedef __bf16 bf16;
typedef __attribute__((ext_vector_type(8))) __bf16 bf16x8;
typedef __attribute__((ext_vector_type(4))) __bf16 bf16x4;
typedef __attribute__((ext_vector_type(4))) float f32x4;
typedef __attribute__((ext_vector_type(4))) unsigned u32x4;

#define DEV __device__ __forceinline__

// fast shifted-softplus: hw v_exp/v_log, err ~1e-6 << bf16 rounding
DEV float sspf(float x) {
    return fmaxf(x, 0.f) + __logf(1.f + __expf(-fabsf(x))) - 0.69314718055994531f;
}

DEV f32x4 mfma16(bf16x8 a, bf16x8 b, f32x4 c) {
    return __builtin_amdgcn_mfma_f32_16x16x32_bf16(a, b, c, 0, 0, 0);
}

DEV float blo(unsigned u) { return __uint_as_float(u << 16); }
DEV float bhi(unsigned u) { return __uint_as_float(u & 0xffff0000u); }

// -------- prep: transpose all weights to [n][k] bf16 -------------------------
struct PrepArgs {
    const float *conv1_w, *conv2_w, *int_lin_w, *mlp_w1, *mlp_w2, *lin1_w, *lin2_w;
    bf16 *c1t, *c2t, *ilt, *w1t, *w2t, *l1t, *l2t;
};

__global__ void prep_kernel(PrepArgs p) {
    int j = blockIdx.x;
    const float* src = nullptr; bf16* dst = nullptr; int R = 0, C = 0, K = 0;
    if (j < 30) {
        int l = j / 5, m = j % 5;
        switch (m) {
            case 0: src = p.conv1_w + l * HH * FF;   dst = p.c1t + l * FF * HH;  R = HH; C = FF; K = HH; break;
            case 1: src = p.conv2_w + l * FF * HH;   dst = p.c2t + l * HH * FF;  R = FF; C = HH; K = FF; break;
            case 2: src = p.int_lin_w + l * HH * HH; dst = p.ilt + l * HH * HH;  R = HH; C = HH; K = HH; break;
            case 3: src = p.mlp_w1 + l * GG * FF;    dst = p.w1t + l * FF * 64;  R = GG; C = FF; K = 64; break;
            case 4: src = p.mlp_w2 + l * FF * FF;    dst = p.w2t + l * FF * FF;  R = FF; C = FF; K = FF; break;
        }
    } else if (j == 30) { src = p.lin1_w; dst = p.l1t; R = HH;  C = H2D; K = HH; }
    else                { src = p.lin2_w; dst = p.l2t; R = H2D; C = H2D; K = H2D; }
    int total = C * K;
    for (int idx = threadIdx.x; idx < total; idx += blockDim.x) {
        int c = idx / K, r = idx - c * K;
        dst[idx] = (r < R) ? (bf16)src[r * C + c] : (bf16)0.f;
    }
}

// -------- table build via MFMA: T[l][r][:] = (ssp(g(d)@W1+b1)@W2+b2)*C(d) ----
__global__ __launch_bounds__(256) void table_kernel(const bf16* __restrict__ w1t,
                                                    const bf16* __restrict__ w2t,
                                                    const float* __restrict__ mlp_b1,
                                                    const float* __restrict__ mlp_b2,
                                                    bf16* __restrict__ tab) {
    __shared__ bf16 sW1[128 * 72];
    __shared__ bf16 sW2[128 * 136];
    __shared__ bf16 sT1[64 * 136];
    int tid = threadIdx.x;
    int l = blockIdx.x / 65, rb = blockIdx.x % 65;
    const bf16* W1 = w1t + (size_t)l * 128 * 64;
    const bf16* W2 = w2t + (size_t)l * 128 * 128;
    for (int idx = tid * 8; idx < 128 * 64; idx += 2048) {
        int n = idx >> 6, k = idx & 63;
        *(bf16x8*)&sW1[n * 72 + k] = *(const bf16x8*)(W1 + idx);
    }
    for (int idx = tid * 8; idx < 128 * 128; idx += 2048) {
        int n = idx >> 7, k = idx & 127;
        *(bf16x8*)&sW2[n * 136 + k] = *(const bf16x8*)(W2 + idx);
    }
    int w = tid >> 6, lane = tid & 63, ln = lane & 15, kg = lane >> 4;
    int rowt = rb * 64 + w * 16;
    float d1 = (float)min(rowt + ln, NK) * (10.f / NK);
    const float step = 10.f / 49.f;
    const float coeff = -0.5f / (step * step);
    __syncthreads();
    // GEMM1: in-register gaussian basis @ W1
    f32x4 acc[8] = {};
#pragma unroll
    for (int k0 = 0; k0 < 64; k0 += 32) {
        bf16x8 a;
#pragma unroll
        for (int jj = 0; jj < 8; jj++) {
            int g = k0 + kg * 8 + jj;
            float diff = d1 - g * step;
            float v = (g < GG) ? __expf(coeff * diff * diff) : 0.f;
            a[jj] = (bf16)v;
        }
#pragma unroll
        for (int t = 0; t < 8; t++) {
            bf16x8 b = *(const bf16x8*)&sW1[(t * 16 + ln) * 72 + k0 + kg * 8];
            acc[t] = mfma16(a, b, acc[t]);
        }
    }
    const float* b1 = mlp_b1 + l * FF;
#pragma unroll
    for (int t = 0; t < 8; t++) {
        int colt = t * 16 + ln;
        float bb = b1[colt];
#pragma unroll
        for (int r = 0; r < 4; r++)
            sT1[(w * 16 + kg * 4 + r) * 136 + colt] = (bf16)sspf(acc[t][r] + bb);
    }
    __syncthreads();
    f32x4 acc2[8] = {};
#pragma unroll
    for (int k0 = 0; k0 < 128; k0 += 32) {
        bf16x8 a = *(const bf16x8*)&sT1[(w * 16 + ln) * 136 + k0 + kg * 8];
#pragma unroll
        for (int t = 0; t < 8; t++) {
            bf16x8 b = *(const bf16x8*)&sW2[(t * 16 + ln) * 136 + k0 + kg * 8];
            acc2[t] = mfma16(a, b, acc2[t]);
        }
    }
    const float* b2 = mlp_b2 + l * FF;
    float Cw[4]; int rrow[4];
#pragma unroll
    for (int r = 0; r < 4; r++) {
        int rr = rowt + kg * 4 + r;
        rrow[r] = rr;
        float dd = (float)min(rr, NK) * (10.f / NK);
        Cw[r] = 0.5f * (cosf(dd * 0.31415926535897932f) + 1.f);
    }
#pragma unroll
    for (int t = 0; t < 8; t++) {
        int colt = t * 16 + ln;
        float bb = b2[colt];
#pragma unroll
        for (int r = 0; r < 4; r++) {
            if (rrow[r] <= NK)
                tab[((size_t)l * (NK + 1) + rrow[r]) * FF + colt] = (bf16)((acc2[t][r] + bb) * Cw[r]);
        }
    }
}

// -------- edge sort by dst: histogram / hierarchical scan / scatter ----------
__global__ void hist_kernel(const int* __restrict__ eidx, int* __restrict__ hist) {
    int e = blockIdx.x * 256 + threadIdx.x;
    if (e < EE) atomicAdd(&hist[eidx[EE + e]], 1);
}

__global__ __launch_bounds__(256) void scanA_kernel(const int* __restrict__ hist,
                                                    int* __restrict__ bsum) {
    __shared__ int red[256];
    int t = threadIdx.x;
    int i = blockIdx.x * 256 + t;
    int v = (i < NN) ? hist[i] : 0;
    red[t] = v;
    __syncthreads();
    for (int off = 128; off > 0; off >>= 1) {
        if (t < off) red[t] += red[t + off];
        __syncthreads();
    }
    if (t == 0) bsum[blockIdx.x] = red[0];
}

__global__ __launch_bounds__(256) void scanB_kernel(int* __restrict__ bsum) {
    __shared__ int buf[256];
    int t = threadIdx.x;
    int v = (t < SB) ? bsum[t] : 0;
    buf[t] = v;
    __syncthreads();
    for (int off = 1; off < 256; off <<= 1) {
        int y = (t >= off) ? buf[t - off] : 0;
        __syncthreads();
        buf[t] += y;
        __syncthreads();
    }
    if (t < SB) bsum[t] = buf[t] - v;   // exclusive
}

__global__ __launch_bounds__(256) void scanC_kernel(const int* __restrict__ hist,
                                                    const int* __restrict__ bsum,
                                                    int* __restrict__ rs,
                                                    int* __restrict__ cur) {
    __shared__ int buf[256];
    int t = threadIdx.x;
    int i = blockIdx.x * 256 + t;
    int v = (i < NN) ? hist[i] : 0;
    buf[t] = v;
    __syncthreads();
    for (int off = 1; off < 256; off <<= 1) {
        int y = (t >= off) ? buf[t - off] : 0;
        __syncthreads();
        buf[t] += y;
        __syncthreads();
    }
    if (i < NN) {
        int ex = buf[t] - v + bsum[blockIdx.x];
        rs[i] = ex;
        cur[i] = ex;
    }
}

// pack (knot index | src<<13) — 4 B per edge
__global__ void scatter_kernel(const float* __restrict__ eattr, const int* __restrict__ eidx,
                               int* __restrict__ cur, int* __restrict__ es) {
    int e = blockIdx.x * 256 + threadIdx.x;
    if (e < EE) {
        int dd = eidx[EE + e];
        int pos = atomicAdd(&cur[dd], 1);
        int k = (int)(eattr[e] * ((float)NK / 10.f) + 0.5f);
        k = min(k, NK);
        es[pos] = k | (eidx[e] << 13);
    }
}

// -------- embed: hb = embedding[x_atoms] (bf16) ------------------------------
__global__ void embed_kernel(const int* __restrict__ x_atoms, const float* __restrict__ emb,
                             bf16* __restrict__ hb) {
    int idx = blockIdx.x * blockDim.x + threadIdx.x;   // over NN*16
    if (idx >= NN * 16) return;
    int n = idx >> 4, ch = idx & 15;
    int a = x_atoms[n];
    const float* ep = emb + a * HH + ch * 8;
    f32x4 v0 = *(const f32x4*)ep;
    f32x4 v1 = *(const f32x4*)(ep + 4);
    bf16x8 vb;
#pragma unroll
    for (int q = 0; q < 4; q++) { vb[q] = (bf16)v0[q]; vb[q + 4] = (bf16)v1[q]; }
    *(bf16x8*)(hb + n * HH + ch * 8) = vb;
}

// -------- xf = hb @ conv1_w  (layer 0 only) ----------------------------------
__global__ __launch_bounds__(256) void xf_kernel(const bf16* __restrict__ hb,
                                                 const bf16* __restrict__ c1t,
                                                 bf16* __restrict__ xf) {
    __shared__ bf16 sB[128 * 136];
    int tid = threadIdx.x;
    for (int idx = tid * 8; idx < 128 * 128; idx += 2048) {
        int n = idx >> 7, k = idx & 127;
        *(bf16x8*)&sB[n * 136 + k] = *(const bf16x8*)(c1t + idx);
    }
    int w = tid >> 6, lane = tid & 63, ln = lane & 15, kg = lane >> 4;
    int rowt = blockIdx.x * 64 + w * 16;
    int arow = min(rowt + ln, NN - 1);
    __syncthreads();
    f32x4 acc[8] = {};
#pragma unroll
    for (int k0 = 0; k0 < 128; k0 += 32) {
        bf16x8 a = *(const bf16x8*)(hb + arow * HH + k0 + kg * 8);
#pragma unroll
        for (int t = 0; t < 8; t++) {
            bf16x8 b = *(const bf16x8*)&sB[(t * 16 + ln) * 136 + k0 + kg * 8];
            acc[t] = mfma16(a, b, acc[t]);
        }
    }
#pragma unroll
    for (int t = 0; t < 8; t++) {
        int colt = t * 16 + ln;
#pragma unroll
        for (int r = 0; r < 4; r++) {
            int orow = rowt + kg * 4 + r;
            if (orow < NN) xf[orow * FF + colt] = (bf16)acc[t][r];
        }
    }
}

// -------- edge kernel: CSR, one wave/node, nearest-knot, 4 edges/iter --------
__global__ __launch_bounds__(256) void edge_kernel(const int* __restrict__ es,
                                                   const int* __restrict__ rs,
                                                   const int* __restrict__ hist,
                                                   const bf16* __restrict__ xf,
                                                   const bf16* __restrict__ tab,
                                                   bf16* __restrict__ aggb) {
    int tid = threadIdx.x;
    int w = tid >> 6, lane = tid & 63;
    int q = lane >> 4, cl = lane & 15;      // quarter q handles edge 4j+q; lane covers ch [8cl,8cl+8)
    int n = blockIdx.x * 4 + w;
    int start = rs[n], deg = hist[n];
    float a0 = 0.f, a1 = 0.f, a2 = 0.f, a3 = 0.f;
    float a4 = 0.f, a5 = 0.f, a6 = 0.f, a7 = 0.f;
    for (int base = 0; base < deg; base += 64) {
        int cnt = min(deg - base, 64);
        int pv = (lane < cnt) ? es[start + base + lane] : 0;
        int iters = (cnt + 3) >> 2;
#pragma unroll 4
        for (int j = 0; j < iters; j++) {
            int jj = 4 * j + q;
            bool valid = jj < cnt;
            int v = __shfl(pv, jj);
            int k = v & 8191;
            int s = v >> 13;
            u32x4 tp = *(const u32x4*)(tab + (size_t)k * FF + 8 * cl);
            u32x4 xu = *(const u32x4*)(xf + (size_t)s * FF + 8 * cl);
            unsigned t0 = valid ? tp.x : 0u;
            unsigned t1 = valid ? tp.y : 0u;
            unsigned t2 = valid ? tp.z : 0u;
            unsigned t3 = valid ? tp.w : 0u;
            a0 = fmaf(blo(t0), blo(xu.x), a0);
            a1 = fmaf(bhi(t0), bhi(xu.x), a1);
            a2 = fmaf(blo(t1), blo(xu.y), a2);
            a3 = fmaf(bhi(t1), bhi(xu.y), a3);
            a4 = fmaf(blo(t2), blo(xu.z), a4);
            a5 = fmaf(bhi(t2), bhi(xu.z), a5);
            a6 = fmaf(blo(t3), blo(xu.w), a6);
            a7 = fmaf(bhi(t3), bhi(xu.w), a7);
        }
    }
    // combine the 4 quarter-partials per channel
    a0 += __shfl_xor(a0, 16); a0 += __shfl_xor(a0, 32);
    a1 += __shfl_xor(a1, 16); a1 += __shfl_xor(a1, 32);
    a2 += __shfl_xor(a2, 16); a2 += __shfl_xor(a2, 32);
    a3 += __shfl_xor(a3, 16); a3 += __shfl_xor(a3, 32);
    a4 += __shfl_xor(a4, 16); a4 += __shfl_xor(a4, 32);
    a5 += __shfl_xor(a5, 16); a5 += __shfl_xor(a5, 32);
    a6 += __shfl_xor(a6, 16); a6 += __shfl_xor(a6, 32);
    a7 += __shfl_xor(a7, 16); a7 += __shfl_xor(a7, 32);
    if (q == 0) {
        bf16x8 pk;
        pk[0] = (bf16)a0; pk[1] = (bf16)a1; pk[2] = (bf16)a2; pk[3] = (bf16)a3;
        pk[4] = (bf16)a4; pk[5] = (bf16)a5; pk[6] = (bf16)a6; pk[7] = (bf16)a7;
        *(bf16x8*)(aggb + (size_t)n * FF + 8 * cl) = pk;
    }
}

// -------- update: hb += ssp(aggb@conv2+b)@int_lin+b; then xf_next | head -----
__global__ __launch_bounds__(256) void update_kernel(const bf16* __restrict__ aggb,
                                                     const bf16* __restrict__ c2t,
                                                     const float* __restrict__ c2b,
                                                     const bf16* __restrict__ ilt,
                                                     const float* __restrict__ ilb,
                                                     bf16* __restrict__ hb,
                                                     const bf16* __restrict__ c1n,
                                                     bf16* __restrict__ xf_out,
                                                     const bf16* __restrict__ l1t,
                                                     const float* __restrict__ l1b,
                                                     const bf16* __restrict__ l2t,
                                                     const float* __restrict__ l2b,
                                                     float* __restrict__ partial) {
    __shared__ bf16 sB[128 * 136];   // restaged per GEMM
    __shared__ bf16 sT[64 * 136];
    int tid = threadIdx.x;
    int w = tid >> 6, lane = tid & 63, ln = lane & 15, kg = lane >> 4;
    int rowt = blockIdx.x * 64 + w * 16;
    int arow = min(rowt + ln, NN - 1);
    // prefetch residual h values needed in epilogue2 (before any barrier)
    float hpre[8][4];
#pragma unroll
    for (int t = 0; t < 8; t++) {
        int colt = t * 16 + ln;
#pragma unroll
        for (int r = 0; r < 4; r++) {
            int orow = rowt + kg * 4 + r;
            hpre[t][r] = (orow < NN) ? (float)hb[(size_t)orow * HH + colt] : 0.f;
        }
    }
    for (int idx = tid * 8; idx < 128 * 128; idx += 2048) {
        int n = idx >> 7, k = idx & 127;
        *(bf16x8*)&sB[n * 136 + k] = *(const bf16x8*)(c2t + idx);
    }
    __syncthreads();
    // GEMM1: aggb @ conv2 (A direct from global bf16)
    f32x4 acc[8] = {};
#pragma unroll
    for (int k0 = 0; k0 < 128; k0 += 32) {
        bf16x8 a = *(const bf16x8*)(aggb + (size_t)arow * FF + k0 + kg * 8);
#pragma unroll
        for (int t = 0; t < 8; t++) {
            bf16x8 b = *(const bf16x8*)&sB[(t * 16 + ln) * 136 + k0 + kg * 8];
            acc[t] = mfma16(a, b, acc[t]);
        }
    }
#pragma unroll
    for (int t = 0; t < 8; t++) {
        int colt = t * 16 + ln;
        float bb = c2b[colt];
#pragma unroll
        for (int r = 0; r < 4; r++)
            sT[(w * 16 + kg * 4 + r) * 136 + colt] = (bf16)sspf(acc[t][r] + bb);
    }
    __syncthreads();
    for (int idx = tid * 8; idx < 128 * 128; idx += 2048) {
        int n = idx >> 7, k = idx & 127;
        *(bf16x8*)&sB[n * 136 + k] = *(const bf16x8*)(ilt + idx);
    }
    __syncthreads();
    f32x4 acc2[8] = {};
#pragma unroll
    for (int k0 = 0; k0 < 128; k0 += 32) {
        bf16x8 a = *(const bf16x8*)&sT[(w * 16 + ln) * 136 + k0 + kg * 8];
#pragma unroll
        for (int t = 0; t < 8; t++) {
            bf16x8 b = *(const bf16x8*)&sB[(t * 16 + ln) * 136 + k0 + kg * 8];
            acc2[t] = mfma16(a, b, acc2[t]);
        }
    }
    bool is_last = (c1n == nullptr);
#pragma unroll
    for (int t = 0; t < 8; t++) {
        int colt = t * 16 + ln;
        float bb = ilb[colt];
#pragma unroll
        for (int r = 0; r < 4; r++) {
            int orow = rowt + kg * 4 + r;
            float hn = hpre[t][r] + acc2[t][r] + bb;
            if (orow < NN && !is_last) hb[(size_t)orow * HH + colt] = (bf16)hn;
            sT[(w * 16 + kg * 4 + r) * 136 + colt] = (bf16)hn;
        }
    }
    if (!is_last) {
        // fused next-layer xf = h_new @ conv1_next
        __syncthreads();
        for (int idx = tid * 8; idx < 128 * 128; idx += 2048) {
            int n = idx >> 7, k = idx & 127;
            *(bf16x8*)&sB[n * 136 + k] = *(const bf16x8*)(c1n + idx);
        }
        __syncthreads();
        f32x4 acc3[8] = {};
#pragma unroll
        for (int k0 = 0; k0 < 128; k0 += 32) {
            bf16x8 a = *(const bf16x8*)&sT[(w * 16 + ln) * 136 + k0 + kg * 8];
#pragma unroll
            for (int t = 0; t < 8; t++) {
                bf16x8 b = *(const bf16x8*)&sB[(t * 16 + ln) * 136 + k0 + kg * 8];
                acc3[t] = mfma16(a, b, acc3[t]);
            }
        }
#pragma unroll
        for (int t = 0; t < 8; t++) {
            int colt = t * 16 + ln;
#pragma unroll
            for (int r = 0; r < 4; r++) {
                int orow = rowt + kg * 4 + r;
                if (orow < NN) xf_out[(size_t)orow * FF + colt] = (bf16)acc3[t][r];
            }
        }
    } else {
        // fused head: ssp(h@lin1+b)@lin2+b, per-block partial sum
        __syncthreads();
        for (int idx = tid * 8; idx < 64 * 128; idx += 2048) {
            int n = idx >> 7, k = idx & 127;
            *(bf16x8*)&sB[n * 136 + k] = *(const bf16x8*)(l1t + idx);
        }
        __syncthreads();
        f32x4 acch[4] = {};
#pragma unroll
        for (int k0 = 0; k0 < 128; k0 += 32) {
            bf16x8 a = *(const bf16x8*)&sT[(w * 16 + ln) * 136 + k0 + kg * 8];
#pragma unroll
            for (int t = 0; t < 4; t++) {
                bf16x8 b = *(const bf16x8*)&sB[(t * 16 + ln) * 136 + k0 + kg * 8];
                acch[t] = mfma16(a, b, acch[t]);
            }
        }
#pragma unroll
        for (int t = 0; t < 4; t++) {
            int colt = t * 16 + ln;
            float bb = l1b[colt];
#pragma unroll
            for (int r = 0; r < 4; r++)
                sT[(w * 16 + kg * 4 + r) * 136 + colt] = (bf16)sspf(acch[t][r] + bb);
        }
        __syncthreads();
        for (int idx = tid * 8; idx < 64 * 64; idx += 2048) {
            int n = idx >> 6, k = idx & 63;
            *(bf16x8*)&sB[n * 136 + k] = *(const bf16x8*)(l2t + idx);
        }
        __syncthreads();
        f32x4 acc2h[4] = {};
#pragma unroll
        for (int k0 = 0; k0 < 64; k0 += 32) {
            bf16x8 a = *(const bf16x8*)&sT[(w * 16 + ln) * 136 + k0 + kg * 8];
#pragma unroll
            for (int t = 0; t < 4; t++) {
                bf16x8 b = *(const bf16x8*)&sB[(t * 16 + ln) * 136 + k0 + kg * 8];
                acc2h[t] = mfma16(a, b, acc2h[t]);
            }
        }
        __syncthreads();   // all sT reads done; reuse as f32 scratch
        float* sPart = (float*)sT;
#pragma unroll
        for (int t = 0; t < 4; t++) {
            int colt = t * 16 + ln;
            float bb = l2b[colt];
            float v = 0.f;
#pragma unroll
            for (int r = 0; r < 4; r++) {
                int orow = rowt + kg * 4 + r;
                if (orow < NN) v += acc2h[t][r] + bb;
            }
            v += __shfl_xor(v, 16);
            v += __shfl_xor(v, 32);
            if (kg == 0) sPart[w * 64 + colt] = v;
        }
        __syncthreads();
        if (tid < 64) {
            float s = sPart[tid] + sPart[64 + tid] + sPart[128 + tid] + sPart[192 + tid];
            partial[blockIdx.x * 64 + tid] = s;
        }
    }
}

__global__ __launch_bounds__(64) void final_kernel(const float* __restrict__ partial,
                                                   const float* __restrict__ rw,
                                                   const float* __restrict__ rb,
                                                   float* __restrict__ out) {
    __shared__ float sv[64];
    int j = threadIdx.x;
    float s = 0.f;
    for (int b = 0; b < NBLK; b++) s += partial[b * 64 + j];
    sv[j] = s;
    __syncthreads();
    if (j < OUT_DIM) {
        float o = rb[j];
        for (int i = 0; i < H2D; i++) o += sv[i] * rw[i * OUT_DIM + j];
        out[j] = o;
    }
}

// -------- launch -------------------------------------------------------------
extern "C" void kernel_launch(void* const* d_in, const int* in_sizes, int n_in,
                              void* d_out, int out_size, void* d_ws, size_t ws_size,
                              hipStream_t stream) {
    const int*   x_atoms    = (const int*)d_in[0];
    const int*   edge_index = (const int*)d_in[1];
    const float* edge_attr  = (const float*)d_in[2];
    const float* embedding  = (const float*)d_in[3];
    const float* mlp_w1     = (const float*)d_in[4];
    const float* mlp_b1     = (const float*)d_in[5];
    const float* mlp_w2     = (const float*)d_in[6];
    const float* mlp_b2     = (const float*)d_in[7];
    const float* conv1_w    = (const float*)d_in[8];
    const float* conv2_w    = (const float*)d_in[9];
    const float* conv2_b    = (const float*)d_in[10];
    const float* int_lin_w  = (const float*)d_in[11];
    const float* int_lin_b  = (const float*)d_in[12];
    const float* lin1_w     = (const float*)d_in[13];
    const float* lin1_b     = (const float*)d_in[14];
    const float* lin2_w     = (const float*)d_in[15];
    const float* lin2_b     = (const float*)d_in[16];
    const float* readout_w  = (const float*)d_in[17];
    const float* readout_b  = (const float*)d_in[18];

    char* ws = (char*)d_ws;
    bf16*  hb      = (bf16*)(ws + 0);              // 12,800,000
    bf16*  xfA     = (bf16*)(ws + 12800000);       // 12,800,000
    bf16*  xfB     = (bf16*)(ws + 25600000);       // 12,800,000
    bf16*  aggb    = (bf16*)(ws + 38400000);       // 12,800,000
    float* partial = (float*)(ws + 51200000);      // 200,192
    size_t wb = 51400192;
    bf16* c1t = (bf16*)(ws + wb);                  // 196,608
    bf16* c2t = (bf16*)(ws + wb + 196608);
    bf16* ilt = (bf16*)(ws + wb + 393216);
    bf16* w1t = (bf16*)(ws + wb + 589824);         // 98,304
    bf16* w2t = (bf16*)(ws + wb + 688128);         // 196,608
    bf16* l1t = (bf16*)(ws + wb + 884736);         // 16,384
    bf16* l2t = (bf16*)(ws + wb + 901120);         // 8,192 -> ends 52,309,504
    int*   d_hist = (int*)(ws + 52309504);         // 200,000
    int*   d_rs   = (int*)(ws + 52509504);         // 200,000
    int*   d_cur  = (int*)(ws + 52709504);         // 200,000
    int*   d_bsum = (int*)(ws + 52909504);         // 1,024
    int*   d_es   = (int*)(ws + 52910528);         // 3,200,000 -> 56,110,528
    bf16*  tab    = (bf16*)(ws + 56110528);        // 6*4097*128*2 = 6,292,992 -> 62,403,520

    PrepArgs pa = { conv1_w, conv2_w, int_lin_w, mlp_w1, mlp_w2, lin1_w, lin2_w,
                    c1t, c2t, ilt, w1t, w2t, l1t, l2t };
    prep_kernel<<<32, 256, 0, stream>>>(pa);
    table_kernel<<<LL * 65, 256, 0, stream>>>(w1t, w2t, mlp_b1, mlp_b2, tab);
    embed_kernel<<<NN * 16 / 256, 256, 0, stream>>>(x_atoms, embedding, hb);

    // sort edges by dst (once; graph static across layers)
    hipMemsetAsync(d_hist, 0, NN * 4, stream);
    hist_kernel<<<(EE + 255) / 256, 256, 0, stream>>>(edge_index, d_hist);
    scanA_kernel<<<SB, 256, 0, stream>>>(d_hist, d_bsum);
    scanB_kernel<<<1, 256, 0, stream>>>(d_bsum);
    scanC_kernel<<<SB, 256, 0, stream>>>(d_hist, d_bsum, d_rs, d_cur);
    scatter_kernel<<<(EE + 255) / 256, 256, 0, stream>>>(edge_attr, edge_index, d_cur, d_es);

    xf_kernel<<<NBLK, 256, 0, stream>>>(hb, c1t, xfA);   // layer 0 xf
    bf16* xf_in = xfA;
    bf16* xf_out = xfB;
    for (int l = 0; l < LL; l++) {
        edge_kernel<<<NN / 4, 256, 0, stream>>>(d_es, d_rs, d_hist, xf_in,
                                                tab + (size_t)l * (NK + 1) * FF, aggb);
        const bf16* c1n = (l + 1 < LL) ? (c1t + (size_t)(l + 1) * FF * HH) : nullptr;
        update_kernel<<<NBLK, 256, 0, stream>>>(aggb, c2t + (size_t)l * HH * FF,
                                                conv2_b + l * HH,
                                                ilt + (size_t)l * HH * HH, int_lin_b + l * HH,
                                                hb, c1n, xf_out,
                                                l1t, lin1_b, l2t, lin2_b, partial);
        bf16* tmp = xf_in; xf_in = xf_out; xf_out = tmp;
    }
    final_kernel<<<1, 64, 0, stream>>>(partial, readout_w, readout_b, (float*)d_out);
}

// Round 11
// 587.546 us; speedup vs baseline: 2.8771x; 1.1141x over previous
//
#include <hip/hip_runtime.h>
#include <hip/hip_bf16.h>
#include <math.h>

#define NN 50000
#define EE 800000
#define HH 128
#define FF 128
#define GG 50
#define LL 6
#define H2D 64
#define OUT_DIM 12
#define NK 4096          // nearest-neighbor table intervals; knots 0..NK (4097)
#define NBLK 782         // ceil(NN/64)
#define SB 196           // scan blocks: ceil(NN/256)
#define NBUK 196         // scatter buckets: 256 nodes each

typedef __bf16 bf16;
typedef __attribute__((ext_vector_type(8))) __bf16 bf16x8;
typedef __attribute__((ext_vector_type(4))) __bf16 bf16x4;
typedef __attribute__((ext_vector_type(4))) float f32x4;
typedef __attribute__((ext_vector_type(4))) unsigned u32x4;

#define DEV __device__ __forceinline__

// fast shifted-softplus: hw v_exp/v_log, err ~1e-6 << bf16 rounding
DEV float sspf(float x) {
    return fmaxf(x, 0.f) + __logf(1.f + __expf(-fabsf(x))) - 0.69314718055994531f;
}

DEV f32x4 mfma16(bf16x8 a, bf16x8 b, f32x4 c) {
    return __builtin_amdgcn_mfma_f32_16x16x32_bf16(a, b, c, 0, 0, 0);
}

DEV float blo(unsigned u) { return __uint_as_float(u << 16); }
DEV float bhi(unsigned u) { return __uint_as_float(u & 0xffff0000u); }

// -------- prep: transpose all weights to [n][k] bf16 -------------------------
struct PrepArgs {
    const float *conv1_w, *conv2_w, *int_lin_w, *mlp_w1, *mlp_w2, *lin1_w, *lin2_w;
    bf16 *c1t, *c2t, *ilt, *w1t, *w2t, *l1t, *l2t;
};

__global__ void prep_kernel(PrepArgs p) {
    int j = blockIdx.x;
    const float* src = nullptr; bf16* dst = nullptr; int R = 0, C = 0, K = 0;
    if (j < 30) {
        int l = j / 5, m = j % 5;
        switch (m) {
            case 0: src = p.conv1_w + l * HH * FF;   dst = p.c1t + l * FF * HH;  R = HH; C = FF; K = HH; break;
            case 1: src = p.conv2_w + l * FF * HH;   dst = p.c2t + l * HH * FF;  R = FF; C = HH; K = FF; break;
            case 2: src = p.int_lin_w + l * HH * HH; dst = p.ilt + l * HH * HH;  R = HH; C = HH; K = HH; break;
            case 3: src = p.mlp_w1 + l * GG * FF;    dst = p.w1t + l * FF * 64;  R = GG; C = FF; K = 64; break;
            case 4: src = p.mlp_w2 + l * FF * FF;    dst = p.w2t + l * FF * FF;  R = FF; C = FF; K = FF; break;
        }
    } else if (j == 30) { src = p.lin1_w; dst = p.l1t; R = HH;  C = H2D; K = HH; }
    else                { src = p.lin2_w; dst = p.l2t; R = H2D; C = H2D; K = H2D; }
    int total = C * K;
    for (int idx = threadIdx.x; idx < total; idx += blockDim.x) {
        int c = idx / K, r = idx - c * K;
        dst[idx] = (r < R) ? (bf16)src[r * C + c] : (bf16)0.f;
    }
}

// -------- table build via MFMA: T[l][r][:] = (ssp(g(d)@W1+b1)@W2+b2)*C(d) ----
__global__ __launch_bounds__(256) void table_kernel(const bf16* __restrict__ w1t,
                                                    const bf16* __restrict__ w2t,
                                                    const float* __restrict__ mlp_b1,
                                                    const float* __restrict__ mlp_b2,
                                                    bf16* __restrict__ tab) {
    __shared__ bf16 sW1[128 * 72];
    __shared__ bf16 sW2[128 * 136];
    __shared__ bf16 sT1[64 * 136];
    int tid = threadIdx.x;
    int l = blockIdx.x / 65, rb = blockIdx.x % 65;
    const bf16* W1 = w1t + (size_t)l * 128 * 64;
    const bf16* W2 = w2t + (size_t)l * 128 * 128;
    for (int idx = tid * 8; idx < 128 * 64; idx += 2048) {
        int n = idx >> 6, k = idx & 63;
        *(bf16x8*)&sW1[n * 72 + k] = *(const bf16x8*)(W1 + idx);
    }
    for (int idx = tid * 8; idx < 128 * 128; idx += 2048) {
        int n = idx >> 7, k = idx & 127;
        *(bf16x8*)&sW2[n * 136 + k] = *(const bf16x8*)(W2 + idx);
    }
    int w = tid >> 6, lane = tid & 63, ln = lane & 15, kg = lane >> 4;
    int rowt = rb * 64 + w * 16;
    float d1 = (float)min(rowt + ln, NK) * (10.f / NK);
    const float step = 10.f / 49.f;
    const float coeff = -0.5f / (step * step);
    __syncthreads();
    // GEMM1: in-register gaussian basis @ W1
    f32x4 acc[8] = {};
#pragma unroll
    for (int k0 = 0; k0 < 64; k0 += 32) {
        bf16x8 a;
#pragma unroll
        for (int jj = 0; jj < 8; jj++) {
            int g = k0 + kg * 8 + jj;
            float diff = d1 - g * step;
            float v = (g < GG) ? __expf(coeff * diff * diff) : 0.f;
            a[jj] = (bf16)v;
        }
#pragma unroll
        for (int t = 0; t < 8; t++) {
            bf16x8 b = *(const bf16x8*)&sW1[(t * 16 + ln) * 72 + k0 + kg * 8];
            acc[t] = mfma16(a, b, acc[t]);
        }
    }
    const float* b1 = mlp_b1 + l * FF;
#pragma unroll
    for (int t = 0; t < 8; t++) {
        int colt = t * 16 + ln;
        float bb = b1[colt];
#pragma unroll
        for (int r = 0; r < 4; r++)
            sT1[(w * 16 + kg * 4 + r) * 136 + colt] = (bf16)sspf(acc[t][r] + bb);
    }
    __syncthreads();
    f32x4 acc2[8] = {};
#pragma unroll
    for (int k0 = 0; k0 < 128; k0 += 32) {
        bf16x8 a = *(const bf16x8*)&sT1[(w * 16 + ln) * 136 + k0 + kg * 8];
#pragma unroll
        for (int t = 0; t < 8; t++) {
            bf16x8 b = *(const bf16x8*)&sW2[(t * 16 + ln) * 136 + k0 + kg * 8];
            acc2[t] = mfma16(a, b, acc2[t]);
        }
    }
    const float* b2 = mlp_b2 + l * FF;
    float Cw[4]; int rrow[4];
#pragma unroll
    for (int r = 0; r < 4; r++) {
        int rr = rowt + kg * 4 + r;
        rrow[r] = rr;
        float dd = (float)min(rr, NK) * (10.f / NK);
        Cw[r] = 0.5f * (cosf(dd * 0.31415926535897932f) + 1.f);
    }
#pragma unroll
    for (int t = 0; t < 8; t++) {
        int colt = t * 16 + ln;
        float bb = b2[colt];
#pragma unroll
        for (int r = 0; r < 4; r++) {
            if (rrow[r] <= NK)
                tab[((size_t)l * (NK + 1) + rrow[r]) * FF + colt] = (bf16)((acc2[t][r] + bb) * Cw[r]);
        }
    }
}

// -------- edge sort by dst: histogram / hierarchical scan --------------------
__global__ void hist_kernel(const int* __restrict__ eidx, int* __restrict__ hist) {
    int e = blockIdx.x * 256 + threadIdx.x;
    if (e < EE) atomicAdd(&hist[eidx[EE + e]], 1);
}

__global__ __launch_bounds__(256) void scanA_kernel(const int* __restrict__ hist,
                                                    int* __restrict__ bsum) {
    __shared__ int red[256];
    int t = threadIdx.x;
    int i = blockIdx.x * 256 + t;
    int v = (i < NN) ? hist[i] : 0;
    red[t] = v;
    __syncthreads();
    for (int off = 128; off > 0; off >>= 1) {
        if (t < off) red[t] += red[t + off];
        __syncthreads();
    }
    if (t == 0) bsum[blockIdx.x] = red[0];
}

__global__ __launch_bounds__(256) void scanB_kernel(int* __restrict__ bsum) {
    __shared__ int buf[256];
    int t = threadIdx.x;
    int v = (t < SB) ? bsum[t] : 0;
    buf[t] = v;
    __syncthreads();
    for (int off = 1; off < 256; off <<= 1) {
        int y = (t >= off) ? buf[t - off] : 0;
        __syncthreads();
        buf[t] += y;
        __syncthreads();
    }
    if (t < SB) bsum[t] = buf[t] - v;   // exclusive
}

__global__ __launch_bounds__(256) void scanC_kernel(const int* __restrict__ hist,
                                                    const int* __restrict__ bsum,
                                                    int* __restrict__ rs) {
    __shared__ int buf[256];
    int t = threadIdx.x;
    int i = blockIdx.x * 256 + t;
    int v = (i < NN) ? hist[i] : 0;
    buf[t] = v;
    __syncthreads();
    for (int off = 1; off < 256; off <<= 1) {
        int y = (t >= off) ? buf[t - off] : 0;
        __syncthreads();
        buf[t] += y;
        __syncthreads();
    }
    if (i < NN) rs[i] = buf[t] - v + bsum[blockIdx.x];
}

// -------- bucketed two-pass scatter (kills 64B-line write amplification) -----
__global__ void bukinit_kernel(const int* __restrict__ rs, int* __restrict__ bucket_cur) {
    int b = threadIdx.x;
    if (b < NBUK) bucket_cur[b] = rs[b * 256];
}

// pass 1: 196 blocks x 4096 edges -> bucket-grouped tmp (int2: packed, dst)
__global__ __launch_bounds__(256) void scat1_kernel(const float* __restrict__ eattr,
                                                    const int* __restrict__ eidx,
                                                    int* __restrict__ bucket_cur,
                                                    int2* __restrict__ tmp8) {
    __shared__ int cnt[NBUK];
    __shared__ int res[NBUK];
    int t = threadIdx.x;
    for (int i = t; i < NBUK; i += 256) cnt[i] = 0;
    __syncthreads();
    int e0 = blockIdx.x * 4096;
    int pv[16], dd[16], bk[16];
#pragma unroll
    for (int i = 0; i < 16; i++) {
        int e = e0 + i * 256 + t;
        if (e < EE) {
            int d = eidx[EE + e];
            int k = (int)(eattr[e] * ((float)NK / 10.f) + 0.5f);
            k = min(k, NK);
            pv[i] = k | (eidx[e] << 13);
            dd[i] = d;
            bk[i] = d >> 8;
            atomicAdd(&cnt[bk[i]], 1);
        } else bk[i] = -1;
    }
    __syncthreads();
    for (int i = t; i < NBUK; i += 256) {
        int c = cnt[i];
        res[i] = (c > 0) ? atomicAdd(&bucket_cur[i], c) : 0;
        cnt[i] = 0;          // reuse as local rank counter
    }
    __syncthreads();
#pragma unroll
    for (int i = 0; i < 16; i++) {
        if (bk[i] >= 0) {
            int rank = atomicAdd(&cnt[bk[i]], 1);
            int2 v; v.x = pv[i]; v.y = dd[i];
            tmp8[res[bk[i]] + rank] = v;
        }
    }
}

// pass 2: one block per bucket -> final dst-sorted es (dense 16KB window)
__global__ __launch_bounds__(256) void scat2_kernel(const int* __restrict__ rs,
                                                    const int2* __restrict__ tmp8,
                                                    int* __restrict__ es) {
    __shared__ int off[256];
    __shared__ int loc[256];
    int b = blockIdx.x, t = threadIdx.x;
    int nb0 = b * 256;
    int nnb = min(256, NN - nb0);          // nodes in this bucket
    int base = rs[nb0];
    int end = (nb0 + 256 < NN) ? rs[nb0 + 256] : EE;
    loc[t] = 0;
    if (t < nnb) off[t] = rs[nb0 + t] - base;
    __syncthreads();
    for (int e = base + t; e < end; e += 256) {
        int2 v = tmp8[e];
        int nl = v.y - nb0;
        int rank = atomicAdd(&loc[nl], 1);
        es[base + off[nl] + rank] = v.x;
    }
}

// -------- embed: hb = embedding[x_atoms] (bf16) ------------------------------
__global__ void embed_kernel(const int* __restrict__ x_atoms, const float* __restrict__ emb,
                             bf16* __restrict__ hb) {
    int idx = blockIdx.x * blockDim.x + threadIdx.x;   // over NN*16
    if (idx >= NN * 16) return;
    int n = idx >> 4, ch = idx & 15;
    int a = x_atoms[n];
    const float* ep = emb + a * HH + ch * 8;
    f32x4 v0 = *(const f32x4*)ep;
    f32x4 v1 = *(const f32x4*)(ep + 4);
    bf16x8 vb;
#pragma unroll
    for (int q = 0; q < 4; q++) { vb[q] = (bf16)v0[q]; vb[q + 4] = (bf16)v1[q]; }
    *(bf16x8*)(hb + n * HH + ch * 8) = vb;
}

// -------- xf = hb @ conv1_w  (layer 0 only) ----------------------------------
__global__ __launch_bounds__(256) void xf_kernel(const bf16* __restrict__ hb,
                                                 const bf16* __restrict__ c1t,
                                                 bf16* __restrict__ xf) {
    __shared__ bf16 sB[128 * 136];
    int tid = threadIdx.x;
    for (int idx = tid * 8; idx < 128 * 128; idx += 2048) {
        int n = idx >> 7, k = idx & 127;
        *(bf16x8*)&sB[n * 136 + k] = *(const bf16x8*)(c1t + idx);
    }
    int w = tid >> 6, lane = tid & 63, ln = lane & 15, kg = lane >> 4;
    int rowt = blockIdx.x * 64 + w * 16;
    int arow = min(rowt + ln, NN - 1);
    __syncthreads();
    f32x4 acc[8] = {};
#pragma unroll
    for (int k0 = 0; k0 < 128; k0 += 32) {
        bf16x8 a = *(const bf16x8*)(hb + arow * HH + k0 + kg * 8);
#pragma unroll
        for (int t = 0; t < 8; t++) {
            bf16x8 b = *(const bf16x8*)&sB[(t * 16 + ln) * 136 + k0 + kg * 8];
            acc[t] = mfma16(a, b, acc[t]);
        }
    }
#pragma unroll
    for (int t = 0; t < 8; t++) {
        int colt = t * 16 + ln;
#pragma unroll
        for (int r = 0; r < 4; r++) {
            int orow = rowt + kg * 4 + r;
            if (orow < NN) xf[orow * FF + colt] = (bf16)acc[t][r];
        }
    }
}

// -------- edge kernel: CSR, one wave/node, nearest-knot, 4 edges/iter --------
__global__ __launch_bounds__(256) void edge_kernel(const int* __restrict__ es,
                                                   const int* __restrict__ rs,
                                                   const int* __restrict__ hist,
                                                   const bf16* __restrict__ xf,
                                                   const bf16* __restrict__ tab,
                                                   bf16* __restrict__ aggb) {
    int tid = threadIdx.x;
    int w = tid >> 6, lane = tid & 63;
    int q = lane >> 4, cl = lane & 15;      // quarter q handles edge 4j+q; lane covers ch [8cl,8cl+8)
    int n = blockIdx.x * 4 + w;
    int start = rs[n], deg = hist[n];
    float a0 = 0.f, a1 = 0.f, a2 = 0.f, a3 = 0.f;
    float a4 = 0.f, a5 = 0.f, a6 = 0.f, a7 = 0.f;
    for (int base = 0; base < deg; base += 64) {
        int cnt = min(deg - base, 64);
        int pv = (lane < cnt) ? es[start + base + lane] : 0;
        int iters = (cnt + 3) >> 2;
#pragma unroll 4
        for (int j = 0; j < iters; j++) {
            int jj = 4 * j + q;
            bool valid = jj < cnt;
            int v = __shfl(pv, jj);
            int k = v & 8191;
            int s = v >> 13;
            u32x4 tp = *(const u32x4*)(tab + (size_t)k * FF + 8 * cl);
            u32x4 xu = *(const u32x4*)(xf + (size_t)s * FF + 8 * cl);
            unsigned t0 = valid ? tp.x : 0u;
            unsigned t1 = valid ? tp.y : 0u;
            unsigned t2 = valid ? tp.z : 0u;
            unsigned t3 = valid ? tp.w : 0u;
            a0 = fmaf(blo(t0), blo(xu.x), a0);
            a1 = fmaf(bhi(t0), bhi(xu.x), a1);
            a2 = fmaf(blo(t1), blo(xu.y), a2);
            a3 = fmaf(bhi(t1), bhi(xu.y), a3);
            a4 = fmaf(blo(t2), blo(xu.z), a4);
            a5 = fmaf(bhi(t2), bhi(xu.z), a5);
            a6 = fmaf(blo(t3), blo(xu.w), a6);
            a7 = fmaf(bhi(t3), bhi(xu.w), a7);
        }
    }
    a0 += __shfl_xor(a0, 16); a0 += __shfl_xor(a0, 32);
    a1 += __shfl_xor(a1, 16); a1 += __shfl_xor(a1, 32);
    a2 += __shfl_xor(a2, 16); a2 += __shfl_xor(a2, 32);
    a3 += __shfl_xor(a3, 16); a3 += __shfl_xor(a3, 32);
    a4 += __shfl_xor(a4, 16); a4 += __shfl_xor(a4, 32);
    a5 += __shfl_xor(a5, 16); a5 += __shfl_xor(a5, 32);
    a6 += __shfl_xor(a6, 16); a6 += __shfl_xor(a6, 32);
    a7 += __shfl_xor(a7, 16); a7 += __shfl_xor(a7, 32);
    if (q == 0) {
        bf16x8 pk;
        pk[0] = (bf16)a0; pk[1] = (bf16)a1; pk[2] = (bf16)a2; pk[3] = (bf16)a3;
        pk[4] = (bf16)a4; pk[5] = (bf16)a5; pk[6] = (bf16)a6; pk[7] = (bf16)a7;
        *(bf16x8*)(aggb + (size_t)n * FF + 8 * cl) = pk;
    }
}

// -------- update: transposed-output GEMMs (thread = 1 node x 4-feat spans) ---
__global__ __launch_bounds__(256) void update_kernel(const bf16* __restrict__ aggb,
                                                     const bf16* __restrict__ c2t,
                                                     const float* __restrict__ c2b,
                                                     const bf16* __restrict__ ilt,
                                                     const float* __restrict__ ilb,
                                                     bf16* __restrict__ hb,
                                                     const bf16* __restrict__ c1n,
                                                     bf16* __restrict__ xf_out,
                                                     const bf16* __restrict__ l1t,
                                                     const float* __restrict__ l1b,
                                                     const bf16* __restrict__ l2t,
                                                     const float* __restrict__ l2b,
                                                     float* __restrict__ partial) {
    __shared__ bf16 sB[128 * 136];   // restaged per GEMM
    __shared__ bf16 sT[64 * 136];
    int tid = threadIdx.x;
    int w = tid >> 6, lane = tid & 63, ln = lane & 15, kg = lane >> 4;
    int rowt = blockIdx.x * 64 + w * 16;
    int nrow = rowt + ln;                 // this thread's node (transposed layout)
    int arow = min(nrow, NN - 1);
    bool rowok = nrow < NN;
    // prefetch residual h: node nrow, feats t*16+kg*4 .. +4
    bf16x4 hpre[8];
#pragma unroll
    for (int t = 0; t < 8; t++)
        hpre[t] = *(const bf16x4*)(hb + (size_t)arow * HH + t * 16 + kg * 4);
    for (int idx = tid * 8; idx < 128 * 128; idx += 2048) {
        int n = idx >> 7, k = idx & 127;
        *(bf16x8*)&sB[n * 136 + k] = *(const bf16x8*)(c2t + idx);
    }
    __syncthreads();
    // GEMM1 (Ct): out[feat][node] = conv2^T @ agg^T  (operand-swapped MFMA)
    f32x4 acc[8] = {};
#pragma unroll
    for (int k0 = 0; k0 < 128; k0 += 32) {
        bf16x8 bfrag = *(const bf16x8*)(aggb + (size_t)arow * FF + k0 + kg * 8);
#pragma unroll
        for (int t = 0; t < 8; t++) {
            bf16x8 afrag = *(const bf16x8*)&sB[(t * 16 + ln) * 136 + k0 + kg * 8];
            acc[t] = mfma16(afrag, bfrag, acc[t]);
        }
    }
    // epilogue1: thread holds feats t*16+kg*4+[0..4) of node nrow -> b64 LDS writes
#pragma unroll
    for (int t = 0; t < 8; t++) {
        f32x4 bb = *(const f32x4*)(c2b + t * 16 + kg * 4);
        bf16x4 pk;
#pragma unroll
        for (int r = 0; r < 4; r++) pk[r] = (bf16)sspf(acc[t][r] + bb[r]);
        *(bf16x4*)&sT[(w * 16 + ln) * 136 + t * 16 + kg * 4] = pk;
    }
    __syncthreads();
    for (int idx = tid * 8; idx < 128 * 128; idx += 2048) {
        int n = idx >> 7, k = idx & 127;
        *(bf16x8*)&sB[n * 136 + k] = *(const bf16x8*)(ilt + idx);
    }
    __syncthreads();
    f32x4 acc2[8] = {};
#pragma unroll
    for (int k0 = 0; k0 < 128; k0 += 32) {
        bf16x8 bfrag = *(const bf16x8*)&sT[(w * 16 + ln) * 136 + k0 + kg * 8];
#pragma unroll
        for (int t = 0; t < 8; t++) {
            bf16x8 afrag = *(const bf16x8*)&sB[(t * 16 + ln) * 136 + k0 + kg * 8];
            acc2[t] = mfma16(afrag, bfrag, acc2[t]);
        }
    }
    bool is_last = (c1n == nullptr);
    // epilogue2: residual add, vector stores (own sT rows only -> no barrier needed)
#pragma unroll
    for (int t = 0; t < 8; t++) {
        f32x4 bb = *(const f32x4*)(ilb + t * 16 + kg * 4);
        bf16x4 pk;
#pragma unroll
        for (int r = 0; r < 4; r++)
            pk[r] = (bf16)((float)hpre[t][r] + acc2[t][r] + bb[r]);
        if (rowok && !is_last) *(bf16x4*)(hb + (size_t)nrow * HH + t * 16 + kg * 4) = pk;
        *(bf16x4*)&sT[(w * 16 + ln) * 136 + t * 16 + kg * 4] = pk;
    }
    if (!is_last) {
        // fused next-layer xf = h_new @ conv1_next (same transposed form)
        __syncthreads();
        for (int idx = tid * 8; idx < 128 * 128; idx += 2048) {
            int n = idx >> 7, k = idx & 127;
            *(bf16x8*)&sB[n * 136 + k] = *(const bf16x8*)(c1n + idx);
        }
        __syncthreads();
        f32x4 acc3[8] = {};
#pragma unroll
        for (int k0 = 0; k0 < 128; k0 += 32) {
            bf16x8 bfrag = *(const bf16x8*)&sT[(w * 16 + ln) * 136 + k0 + kg * 8];
#pragma unroll
            for (int t = 0; t < 8; t++) {
                bf16x8 afrag = *(const bf16x8*)&sB[(t * 16 + ln) * 136 + k0 + kg * 8];
                acc3[t] = mfma16(afrag, bfrag, acc3[t]);
            }
        }
#pragma unroll
        for (int t = 0; t < 8; t++) {
            bf16x4 pk;
#pragma unroll
            for (int r = 0; r < 4; r++) pk[r] = (bf16)acc3[t][r];
            if (rowok) *(bf16x4*)(xf_out + (size_t)nrow * FF + t * 16 + kg * 4) = pk;
        }
    } else {
        // fused head: ssp(h@lin1+b)@lin2+b, per-block partial sum (runs once)
        __syncthreads();
        for (int idx = tid * 8; idx < 64 * 128; idx += 2048) {
            int n = idx >> 7, k = idx & 127;
            *(bf16x8*)&sB[n * 136 + k] = *(const bf16x8*)(l1t + idx);
        }
        __syncthreads();
        f32x4 acch[4] = {};
#pragma unroll
        for (int k0 = 0; k0 < 128; k0 += 32) {
            bf16x8 a = *(const bf16x8*)&sT[(w * 16 + ln) * 136 + k0 + kg * 8];
#pragma unroll
            for (int t = 0; t < 4; t++) {
                bf16x8 b = *(const bf16x8*)&sB[(t * 16 + ln) * 136 + k0 + kg * 8];
                acch[t] = mfma16(a, b, acch[t]);
            }
        }
#pragma unroll
        for (int t = 0; t < 4; t++) {
            int colt = t * 16 + ln;
            float bb = l1b[colt];
#pragma unroll
            for (int r = 0; r < 4; r++)
                sT[(w * 16 + kg * 4 + r) * 136 + colt] = (bf16)sspf(acch[t][r] + bb);
        }
        __syncthreads();
        for (int idx = tid * 8; idx < 64 * 64; idx += 2048) {
            int n = idx >> 6, k = idx & 63;
            *(bf16x8*)&sB[n * 136 + k] = *(const bf16x8*)(l2t + idx);
        }
        __syncthreads();
        f32x4 acc2h[4] = {};
#pragma unroll
        for (int k0 = 0; k0 < 64; k0 += 32) {
            bf16x8 a = *(const bf16x8*)&sT[(w * 16 + ln) * 136 + k0 + kg * 8];
#pragma unroll
            for (int t = 0; t < 4; t++) {
                bf16x8 b = *(const bf16x8*)&sB[(t * 16 + ln) * 136 + k0 + kg * 8];
                acc2h[t] = mfma16(a, b, acc2h[t]);
            }
        }
        __syncthreads();   // all sT reads done; reuse as f32 scratch
        float* sPart = (float*)sT;
#pragma unroll
        for (int t = 0; t < 4; t++) {
            int colt = t * 16 + ln;
            float bb = l2b[colt];
            float v = 0.f;
#pragma unroll
            for (int r = 0; r < 4; r++) {
                int orow = rowt + kg * 4 + r;
                if (orow < NN) v += acc2h[t][r] + bb;
            }
            v += __shfl_xor(v, 16);
            v += __shfl_xor(v, 32);
            if (kg == 0) sPart[w * 64 + colt] = v;
        }
        __syncthreads();
        if (tid < 64) {
            float s = sPart[tid] + sPart[64 + tid] + sPart[128 + tid] + sPart[192 + tid];
            partial[blockIdx.x * 64 + tid] = s;
        }
    }
}

__global__ __launch_bounds__(64) void final_kernel(const float* __restrict__ partial,
                                                   const float* __restrict__ rw,
                                                   const float* __restrict__ rb,
                                                   float* __restrict__ out) {
    __shared__ float sv[64];
    int j = threadIdx.x;
    float s = 0.f;
    for (int b = 0; b < NBLK; b++) s += partial[b * 64 + j];
    sv[j] = s;
    __syncthreads();
    if (j < OUT_DIM) {
        float o = rb[j];
        for (int i = 0; i < H2D; i++) o += sv[i] * rw[i * OUT_DIM + j];
        out[j] = o;
    }
}

// -------- launch -------------------------------------------------------------
extern "C" void kernel_launch(void* const* d_in, const int* in_sizes, int n_in,
                              void* d_out, int out_size, void* d_ws, size_t ws_size,
                              hipStream_t stream) {
    const int*   x_atoms    = (const int*)d_in[0];
    const int*   edge_index = (const int*)d_in[1];
    const float* edge_attr  = (const float*)d_in[2];
    const float* embedding  = (const float*)d_in[3];
    const float* mlp_w1     = (const float*)d_in[4];
    const float* mlp_b1     = (const float*)d_in[5];
    const float* mlp_w2     = (const float*)d_in[6];
    const float* mlp_b2     = (const float*)d_in[7];
    const float* conv1_w    = (const float*)d_in[8];
    const float* conv2_w    = (const float*)d_in[9];
    const float* conv2_b    = (const float*)d_in[10];
    const float* int_lin_w  = (const float*)d_in[11];
    const float* int_lin_b  = (const float*)d_in[12];
    const float* lin1_w     = (const float*)d_in[13];
    const float* lin1_b     = (const float*)d_in[14];
    const float* lin2_w     = (const float*)d_in[15];
    const float* lin2_b     = (const float*)d_in[16];
    const float* readout_w  = (const float*)d_in[17];
    const float* readout_b  = (const float*)d_in[18];

    char* ws = (char*)d_ws;
    bf16*  hb      = (bf16*)(ws + 0);              // 12,800,000
    bf16*  xfA     = (bf16*)(ws + 12800000);       // 12,800,000
    bf16*  xfB     = (bf16*)(ws + 25600000);       // 12,800,000
    bf16*  aggb    = (bf16*)(ws + 38400000);       // 12,800,000
    float* partial = (float*)(ws + 51200000);      // 200,192
    size_t wb = 51400192;
    bf16* c1t = (bf16*)(ws + wb);                  // 196,608
    bf16* c2t = (bf16*)(ws + wb + 196608);
    bf16* ilt = (bf16*)(ws + wb + 393216);
    bf16* w1t = (bf16*)(ws + wb + 589824);         // 98,304
    bf16* w2t = (bf16*)(ws + wb + 688128);         // 196,608
    bf16* l1t = (bf16*)(ws + wb + 884736);         // 16,384
    bf16* l2t = (bf16*)(ws + wb + 901120);         // 8,192 -> ends 52,309,504
    int*   d_hist = (int*)(ws + 52309504);         // 200,000
    int*   d_rs   = (int*)(ws + 52509504);         // 200,000
    int*   d_bcur = (int*)(ws + 52709504);         // 1,024 (bucket_cur)
    int*   d_bsum = (int*)(ws + 52710528);         // 1,024
    int*   d_es   = (int*)(ws + 52711552);         // 3,200,000 -> 55,911,552
    bf16*  tab    = (bf16*)(ws + 55911552);        // 6*4097*128*2 = 6,292,992 -> 62,204,544
    int2*  d_tmp8 = (int2*)(ws + 62204544);        // 6,400,000 -> 68,604,544

    PrepArgs pa = { conv1_w, conv2_w, int_lin_w, mlp_w1, mlp_w2, lin1_w, lin2_w,
                    c1t, c2t, ilt, w1t, w2t, l1t, l2t };
    prep_kernel<<<32, 256, 0, stream>>>(pa);
    table_kernel<<<LL * 65, 256, 0, stream>>>(w1t, w2t, mlp_b1, mlp_b2, tab);
    embed_kernel<<<NN * 16 / 256, 256, 0, stream>>>(x_atoms, embedding, hb);

    // sort edges by dst (once; graph static across layers)
    hipMemsetAsync(d_hist, 0, NN * 4, stream);
    hist_kernel<<<(EE + 255) / 256, 256, 0, stream>>>(edge_index, d_hist);
    scanA_kernel<<<SB, 256, 0, stream>>>(d_hist, d_bsum);
    scanB_kernel<<<1, 256, 0, stream>>>(d_bsum);
    scanC_kernel<<<SB, 256, 0, stream>>>(d_hist, d_bsum, d_rs);
    bukinit_kernel<<<1, 256, 0, stream>>>(d_rs, d_bcur);
    scat1_kernel<<<NBUK, 256, 0, stream>>>(edge_attr, edge_index, d_bcur, d_tmp8);
    scat2_kernel<<<NBUK, 256, 0, stream>>>(d_rs, d_tmp8, d_es);

    xf_kernel<<<NBLK, 256, 0, stream>>>(hb, c1t, xfA);   // layer 0 xf
    bf16* xf_in = xfA;
    bf16* xf_out = xfB;
    for (int l = 0; l < LL; l++) {
        edge_kernel<<<NN / 4, 256, 0, stream>>>(d_es, d_rs, d_hist, xf_in,
                                                tab + (size_t)l * (NK + 1) * FF, aggb);
        const bf16* c1n = (l + 1 < LL) ? (c1t + (size_t)(l + 1) * FF * HH) : nullptr;
        update_kernel<<<NBLK, 256, 0, stream>>>(aggb, c2t + (size_t)l * HH * FF,
                                                conv2_b + l * HH,
                                                ilt + (size_t)l * HH * HH, int_lin_b + l * HH,
                                                hb, c1n, xf_out,
                                                l1t, lin1_b, l2t, lin2_b, partial);
        bf16* tmp = xf_in; xf_in = xf_out; xf_out = tmp;
    }
    final_kernel<<<1, 64, 0, stream>>>(partial, readout_w, readout_b, (float*)d_out);
}